// Round 8
// baseline (312.578 us; speedup 1.0000x reference)
//
#include <hip/hip_runtime.h>
#include <math.h>

#define NB   8
#define NPTS 1024
#define PTS  8192      // NB*NPTS
#define KNN  16
#define PK   (PTS*KNN) // 131072

typedef __attribute__((ext_vector_type(8))) _Float16 f16x8;
typedef __attribute__((ext_vector_type(4))) float f32x4;
typedef __attribute__((ext_vector_type(16))) float f32x16;

__device__ __forceinline__ unsigned short f2h(float f) {
  _Float16 h = (_Float16)f;
  union { _Float16 h; unsigned short u; } c; c.h = h;
  return c.u;
}
__device__ __forceinline__ float h2f(unsigned short u) {
  union { unsigned short u; _Float16 h; } c; c.u = u;
  return (float)c.h;
}
__device__ __forceinline__ int lanerank(unsigned long long m) {
  return __builtin_amdgcn_mbcnt_hi((unsigned)(m >> 32),
         __builtin_amdgcn_mbcnt_lo((unsigned)m, 0));
}

// ---------------- kNN + conv1 layer1 fused: one WAVE per point ----------------
// R3 WIN: bitonic sort replaced by exact radix-SELECT; 54.7 -> <45 µs.
__global__ __launch_bounds__(256) void knn_conv1_kernel(const float* __restrict__ pos,
    const float* __restrict__ W1, const float* __restrict__ b1,
    int* __restrict__ idx, float* __restrict__ rel,
    unsigned short* __restrict__ z1h, float* __restrict__ mid1) {
  __shared__ float px[NPTS], py[NPTS], pz[NPTS];
  __shared__ float feat[4][KNN][6];
  __shared__ float ls[256], ls2[256];
  const int t = threadIdx.x;
  const int wv = t >> 6, lane = t & 63;
  const int b = blockIdx.x;
  const int graph = b >> 8;
  const int base = graph << 10;
  for (int j = t; j < NPTS; j += 256) {
    px[j] = pos[3*(base+j)];
    py[j] = pos[3*(base+j)+1];
    pz[j] = pos[3*(base+j)+2];
  }
  __syncthreads();

  const int il = ((b & 255) << 2) + wv;
  const int i  = base + il;
  const float pix = px[il], piy = py[il], piz = pz[il];
  const float sqi = pix*pix + piy*piy + piz*piz;

  unsigned key[16];
  #pragma unroll
  for (int q = 0; q < 16; ++q) {
    const int j = (q << 6) + lane;
    const float x = px[j], y = py[j], z = pz[j];
    const float sqj = x*x + y*y + z*z;
    const float dt  = pix*x + piy*y + piz*z;
    const float d   = sqi + sqj - 2.0f*dt;
    const unsigned db = __float_as_uint(d);
    key[q] = (db >> 31) ? ~db : (db | 0x80000000u);
  }

  unsigned V = 0;
  #pragma unroll 1
  for (int bb = 31; bb >= 0; --bb) {
    const unsigned test = V | (1u << bb);
    int cnt = 0;
    #pragma unroll
    for (int q = 0; q < 16; ++q)
      cnt += __popcll(__ballot(key[q] < test));
    if (cnt < 16) V = test;
  }

  int c = 0;
  #pragma unroll
  for (int q = 0; q < 16; ++q)
    c += __popcll(__ballot(key[q] < V));

  int p_lt = 0, p_eq = c;
  #pragma unroll 1
  for (int q = 0; q < 16; ++q) {
    const unsigned long long mlt = __ballot(key[q] < V);
    const unsigned long long meq = __ballot(key[q] == V);
    int slot = -1;
    if (key[q] < V) slot = p_lt + lanerank(mlt);
    else if (key[q] == V) {
      const int s = p_eq + lanerank(meq);
      if (s < 16) slot = s;
    }
    if (slot >= 0) {
      const int j = (q << 6) + lane;
      const int r = i*KNN + slot;
      const float rx = px[j] - pix, ry = py[j] - piy, rz = pz[j] - piz;
      idx[r] = base + j;
      rel[3*r] = rx; rel[3*r+1] = ry; rel[3*r+2] = rz;
      feat[wv][slot][0] = px[j]; feat[wv][slot][1] = py[j]; feat[wv][slot][2] = pz[j];
      feat[wv][slot][3] = rx;    feat[wv][slot][4] = ry;    feat[wv][slot][5] = rz;
    }
    p_lt += __popcll(mlt);
    p_eq += __popcll(meq);
  }

  float w[6];
  #pragma unroll
  for (int q = 0; q < 6; ++q) w[q] = W1[q*64 + lane];
  const float bbv = b1[lane];
  float s = 0.0f, s2 = 0.0f;
  #pragma unroll
  for (int k = 0; k < KNN; ++k) {
    float z = bbv;
    #pragma unroll
    for (int q = 0; q < 6; ++q) z += feat[wv][k][q]*w[q];
    z1h[(size_t)(i*KNN + k)*64 + lane] = f2h(z);
    s += z; s2 += z*z;
  }
  ls[t] = s; ls2[t] = s2;
  __syncthreads();
  if (t < 64) {
    float a  = ls[t] + ls[t+64] + ls[t+128] + ls[t+192];
    float a2 = ls2[t] + ls2[t+64] + ls2[t+128] + ls2[t+192];
    const int cp = (b & 7) * 128;
    atomicAdd(&mid1[cp + t], a);
    atomicAdd(&mid1[cp + 64 + t], a2);
  }
}

// ---------------- weight prep (block 140 zeroes mid1/midA/midB) ----------------
// R8: W3T emitted in 32x32x16 MFMA-FRAGMENT ORDER: fragment (ct,ks) = 1 KB, lane-major:
//   W3T[((ct*8+ks)<<9) + lane*8 + e] = W3[k = ks*16 + (lane>>5)*8 + e][n = ct*32 + (lane&31)]
__global__ __launch_bounds__(256) void wprep_kernel(const float* __restrict__ W3,
    const float* __restrict__ W2, const float* __restrict__ W1c2,
    const float* __restrict__ W2c1,
    unsigned short* __restrict__ W3T, unsigned short* __restrict__ W2T,
    unsigned short* __restrict__ w1T, unsigned short* __restrict__ W2c1T,
    float* __restrict__ mids) {
  const int b = blockIdx.x, t = threadIdx.x;
  if (b < 128) {
    const int k = b;
    const int ks = k >> 4, half = (k >> 3) & 1, e = k & 7;
    for (int n = t; n < 1024; n += 256) {
      const int ct = n >> 5, cc = n & 31;
      W3T[((ct*8 + ks) << 9) + (half*32 + cc)*8 + e] = f2h(W3[(size_t)k*1024 + n]);
    }
  } else if (b < 132) {
    for (int id = (b-128)*2048 + t; id < (b-127)*2048; id += 256) {
      const int n = id >> 6, k = id & 63;
      W2T[n*64 + k] = f2h(W2[k*128 + n]);
    }
  } else if (b < 136) {
    for (int id = (b-132)*1024 + t; id < (b-131)*1024; id += 256) {
      const int n = id >> 6, k = id & 63;
      w1T[n*64 + k] = f2h(W1c2[k*64 + n]);
    }
  } else if (b < 140) {
    for (int id = (b-136)*1024 + t; id < (b-135)*1024; id += 256) {
      const int n = id >> 6, k = id & 63;
      W2c1T[n*64 + k] = f2h(W2c1[k*64 + n]);
    }
  } else {
    for (int i2 = t; i2 < 4096; i2 += 256) mids[i2] = 0.0f;
  }
}

// ---------------- conv1 layer2 + max ----------------
__global__ __launch_bounds__(256) void conv1_l2max_mfma(
    const unsigned short* __restrict__ z1h, const float* __restrict__ mid1,
    const float* __restrict__ g1, const float* __restrict__ be1,
    const unsigned short* __restrict__ W2T, const float* __restrict__ b2,
    unsigned short* __restrict__ x1h) {
  __shared__ unsigned short As[128*64];
  __shared__ float scl[64], shl[64];
  const int r0 = blockIdx.x * 128;
  const int t = threadIdx.x;
  const int lane = t & 63, w = t >> 6;
  const int quad = lane >> 4, mcol = lane & 15;
  const float invR = 1.0f / (float)PK;

  if (t < 64) {
    float s = 0.0f, s2 = 0.0f;
    #pragma unroll
    for (int k = 0; k < 8; ++k) { s += mid1[k*128 + t]; s2 += mid1[k*128 + 64 + t]; }
    const float mu  = s * invR;
    const float var = s2 * invR - mu*mu;
    const float sc  = g1[t] * rsqrtf(var + 1e-5f);
    scl[t] = sc; shl[t] = be1[t] - mu*sc;
  }
  __syncthreads();

  {
    const int kb = t & 7, rr = t >> 3;
    float sc[8], sh[8];
    #pragma unroll
    for (int q = 0; q < 8; ++q) { sc[q] = scl[kb*8 + q]; sh[q] = shl[kb*8 + q]; }
    #pragma unroll
    for (int it = 0; it < 4; ++it) {
      const int r = rr + it*32;
      union { uint4 v; unsigned short s[8]; } in;
      in.v = *(const uint4*)(z1h + (size_t)(r0 + r)*64 + kb*8);
      union { unsigned short s[8]; uint4 v; } o;
      #pragma unroll
      for (int q = 0; q < 8; ++q)
        o.s[q] = f2h(fmaxf(h2f(in.s[q])*sc[q] + sh[q], 0.0f));
      *(uint4*)(As + r*64 + ((kb ^ (r & 7)) * 8)) = o.v;
    }
  }
  __syncthreads();

  const int wrow = (w >> 1) * 64;
  const int wncol = (w & 1) * 32;

  f32x4 acc[4][2];
  #pragma unroll
  for (int mi = 0; mi < 4; ++mi)
    #pragma unroll
    for (int ni = 0; ni < 2; ++ni)
      acc[mi][ni] = (f32x4){0.f, 0.f, 0.f, 0.f};

  #pragma unroll
  for (int ks = 0; ks < 2; ++ks) {
    f16x8 af[4], bfr[2];
    #pragma unroll
    for (int mi = 0; mi < 4; ++mi) {
      const int row = wrow + mi*16 + mcol;
      af[mi] = *(const f16x8*)(As + row*64 + (((ks*4 + quad) ^ (row & 7)) * 8));
    }
    #pragma unroll
    for (int ni = 0; ni < 2; ++ni) {
      const int nr = wncol + ni*16 + mcol;
      bfr[ni] = *(const f16x8*)(W2T + nr*64 + ks*32 + quad*8);
    }
    #pragma unroll
    for (int mi = 0; mi < 4; ++mi)
      #pragma unroll
      for (int ni = 0; ni < 2; ++ni)
        acc[mi][ni] = __builtin_amdgcn_mfma_f32_16x16x32_f16(af[mi], bfr[ni], acc[mi][ni], 0, 0, 0);
  }

  float bb[2];
  #pragma unroll
  for (int ni = 0; ni < 2; ++ni) bb[ni] = b2[wncol + ni*16 + mcol];
  #pragma unroll
  for (int mi = 0; mi < 4; ++mi) {
    const int p = blockIdx.x*8 + (w >> 1)*4 + mi;
    #pragma unroll
    for (int ni = 0; ni < 2; ++ni) {
      f32x4 a = acc[mi][ni];
      float m = fmaxf(fmaxf(a[0], a[1]), fmaxf(a[2], a[3]));
      m = fmaxf(m, __shfl_xor(m, 16));
      m = fmaxf(m, __shfl_xor(m, 32));
      if (quad == 0) x1h[(size_t)p*64 + wncol + ni*16 + mcol] = f2h(m + bb[ni]);
    }
  }
}

// ---------------- conv2 layer1: fp16 MFMA (gather + rank-3 rel fixup) ----------------
__global__ __launch_bounds__(256) void conv2_l1_mfma(
    const unsigned short* __restrict__ x1h, const int* __restrict__ idx,
    const float* __restrict__ rel, const unsigned short* __restrict__ w1T,
    const float* __restrict__ W1full, const float* __restrict__ b1,
    unsigned short* __restrict__ zah, float* __restrict__ midA) {
  __shared__ unsigned short S[128*64];
  __shared__ int   idxr[128];
  __shared__ float rl[128*3];
  __shared__ float ps[256];
  const int r0 = blockIdx.x * 128;
  const int t = threadIdx.x;
  const int lane = t & 63, w = t >> 6;
  const int quad = lane >> 4, mcol = lane & 15;

  if (t < 128) idxr[t] = idx[r0 + t];
  else if (t < 224) *(float4*)(rl + (t-128)*4) = *(const float4*)(rel + (size_t)r0*3 + (t-128)*4);
  __syncthreads();

  {
    const int kb = t & 7, rr = t >> 3;
    #pragma unroll
    for (int it = 0; it < 4; ++it) {
      const int r = rr + it*32;
      const int gj = idxr[r];
      const uint4 v = *(const uint4*)(x1h + (size_t)gj*64 + kb*8);
      *(uint4*)(S + r*64 + ((kb ^ (r & 7)) * 8)) = v;
    }
  }
  __syncthreads();

  const int wrow = (w >> 1) * 64;
  const int wcol = (w & 1) * 32;

  f16x8 af[2][4], bfr[2][2];
  #pragma unroll
  for (int ks = 0; ks < 2; ++ks)
    #pragma unroll
    for (int mi = 0; mi < 4; ++mi) {
      const int row = wrow + mi*16 + mcol;
      af[ks][mi] = *(const f16x8*)(S + row*64 + (((ks*4 + quad) ^ (row & 7)) * 8));
    }
  #pragma unroll
  for (int ks = 0; ks < 2; ++ks)
    #pragma unroll
    for (int ni = 0; ni < 2; ++ni) {
      const int nr = wcol + ni*16 + mcol;
      bfr[ks][ni] = *(const f16x8*)(w1T + nr*64 + ks*32 + quad*8);
    }

  f32x4 acc[4][2];
  #pragma unroll
  for (int mi = 0; mi < 4; ++mi)
    #pragma unroll
    for (int ni = 0; ni < 2; ++ni)
      acc[mi][ni] = (f32x4){0.f, 0.f, 0.f, 0.f};

  #pragma unroll
  for (int ks = 0; ks < 2; ++ks)
    #pragma unroll
    for (int mi = 0; mi < 4; ++mi)
      #pragma unroll
      for (int ni = 0; ni < 2; ++ni)
        acc[mi][ni] = __builtin_amdgcn_mfma_f32_16x16x32_f16(af[ks][mi], bfr[ks][ni], acc[mi][ni], 0, 0, 0);

  __syncthreads();

  float bb[2], wr0[2], wr1[2], wr2[2];
  #pragma unroll
  for (int ni = 0; ni < 2; ++ni) {
    const int col = wcol + ni*16 + mcol;
    bb[ni]  = b1[col];
    wr0[ni] = W1full[64*64 + col];
    wr1[ni] = W1full[65*64 + col];
    wr2[ni] = W1full[66*64 + col];
  }
  float s[2] = {0,0}, s2[2] = {0,0};
  #pragma unroll
  for (int mi = 0; mi < 4; ++mi) {
    #pragma unroll
    for (int j = 0; j < 4; ++j) {
      const int row = wrow + mi*16 + quad*4 + j;
      const float r0v = rl[row*3], r1v = rl[row*3+1], r2v = rl[row*3+2];
      #pragma unroll
      for (int ni = 0; ni < 2; ++ni) {
        const int col = wcol + ni*16 + mcol;
        const int g = col >> 3, o = col & 7;
        const float v = acc[mi][ni][j] + bb[ni] + r0v*wr0[ni] + r1v*wr1[ni] + r2v*wr2[ni];
        S[row*64 + ((g ^ (row & 7)) << 3) + o] = f2h(v);
        s[ni] += v; s2[ni] += v*v;
      }
    }
  }
  #pragma unroll
  for (int ni = 0; ni < 2; ++ni) {
    s[ni]  += __shfl_xor(s[ni], 16);  s[ni]  += __shfl_xor(s[ni], 32);
    s2[ni] += __shfl_xor(s2[ni], 16); s2[ni] += __shfl_xor(s2[ni], 32);
  }
  if (quad == 0) {
    const int rh = w >> 1;
    #pragma unroll
    for (int ni = 0; ni < 2; ++ni) {
      const int col = wcol + ni*16 + mcol;
      ps[rh*128 + col]      = s[ni];
      ps[rh*128 + 64 + col] = s2[ni];
    }
  }
  __syncthreads();

  #pragma unroll
  for (int i = 0; i < 4; ++i) {
    const int u = i*256 + t;
    const int row = u >> 3, gg = u & 7;
    *(uint4*)(zah + (size_t)(r0 + row)*64 + gg*8) =
        *(const uint4*)(S + row*64 + ((gg ^ (row & 7)) << 3));
  }
  if (t < 128) atomicAdd(&midA[(blockIdx.x & 7)*128 + t], ps[t] + ps[128 + t]);
}

// ---------------- conv2 layer2: fp16 MFMA; BN from 8-copy midA ----------------
__global__ __launch_bounds__(256) void conv2_l2_mfma(
    const unsigned short* __restrict__ zah, const float* __restrict__ midA,
    const float* __restrict__ g1, const float* __restrict__ be1,
    const unsigned short* __restrict__ W2T, const float* __restrict__ b2,
    unsigned short* __restrict__ zhb, float* __restrict__ midB) {
  __shared__ unsigned short S[128*128];
  __shared__ float ps[512];
  __shared__ float scl[64], shl[64];
  const int r0 = blockIdx.x * 128;
  const int t = threadIdx.x;
  const int lane = t & 63, w = t >> 6;
  const int quad = lane >> 4, mcol = lane & 15;
  const float invR = 1.0f / (float)PK;

  if (t < 64) {
    float s = 0.0f, s2 = 0.0f;
    #pragma unroll
    for (int k = 0; k < 8; ++k) { s += midA[k*128 + t]; s2 += midA[k*128 + 64 + t]; }
    const float mu  = s * invR;
    const float var = s2 * invR - mu*mu;
    const float sc  = g1[t] * rsqrtf(var + 1e-5f);
    scl[t] = sc; shl[t] = be1[t] - mu*sc;
  }
  __syncthreads();

  {
    const int kb = t & 7, rr = t >> 3;
    float sc[8], sh[8];
    #pragma unroll
    for (int q = 0; q < 8; ++q) { sc[q] = scl[kb*8 + q]; sh[q] = shl[kb*8 + q]; }
    #pragma unroll
    for (int it = 0; it < 4; ++it) {
      const int r = rr + it*32;
      union { uint4 v; unsigned short s[8]; } in;
      in.v = *(const uint4*)(zah + (size_t)(r0 + r)*64 + kb*8);
      union { unsigned short s[8]; uint4 v; } o;
      #pragma unroll
      for (int q = 0; q < 8; ++q)
        o.s[q] = f2h(fmaxf(h2f(in.s[q])*sc[q] + sh[q], 0.0f));
      *(uint4*)(S + r*64 + ((kb ^ (r & 7)) * 8)) = o.v;
    }
  }
  __syncthreads();

  const int wrow = (w >> 1) * 64;
  const int wcol = (w & 1) * 64;

  f16x8 af[2][4], bfr[2][4];
  #pragma unroll
  for (int ks = 0; ks < 2; ++ks)
    #pragma unroll
    for (int mi = 0; mi < 4; ++mi) {
      const int row = wrow + mi*16 + mcol;
      af[ks][mi] = *(const f16x8*)(S + row*64 + (((ks*4 + quad) ^ (row & 7)) * 8));
    }
  #pragma unroll
  for (int ks = 0; ks < 2; ++ks)
    #pragma unroll
    for (int ni = 0; ni < 4; ++ni) {
      const int nr = wcol + ni*16 + mcol;
      bfr[ks][ni] = *(const f16x8*)(W2T + nr*64 + ks*32 + quad*8);
    }

  f32x4 acc[4][4];
  #pragma unroll
  for (int mi = 0; mi < 4; ++mi)
    #pragma unroll
    for (int ni = 0; ni < 4; ++ni)
      acc[mi][ni] = (f32x4){0.f, 0.f, 0.f, 0.f};

  #pragma unroll
  for (int ks = 0; ks < 2; ++ks)
    #pragma unroll
    for (int mi = 0; mi < 4; ++mi)
      #pragma unroll
      for (int ni = 0; ni < 4; ++ni)
        acc[mi][ni] = __builtin_amdgcn_mfma_f32_16x16x32_f16(af[ks][mi], bfr[ks][ni], acc[mi][ni], 0, 0, 0);

  __syncthreads();

  float bb[4];
  #pragma unroll
  for (int ni = 0; ni < 4; ++ni) bb[ni] = b2[wcol + ni*16 + mcol];
  float s[4] = {0,0,0,0}, s2[4] = {0,0,0,0};
  #pragma unroll
  for (int mi = 0; mi < 4; ++mi) {
    #pragma unroll
    for (int ni = 0; ni < 4; ++ni) {
      const int col = wcol + ni*16 + mcol;
      const int g = col >> 3, o = col & 7;
      #pragma unroll
      for (int j = 0; j < 4; ++j) {
        const int row = wrow + mi*16 + quad*4 + j;
        const float v = acc[mi][ni][j] + bb[ni];
        S[row*128 + ((g ^ (row & 15)) << 3) + o] = f2h(v);
        s[ni] += v; s2[ni] += v*v;
      }
    }
  }
  #pragma unroll
  for (int ni = 0; ni < 4; ++ni) {
    s[ni]  += __shfl_xor(s[ni], 16);  s[ni]  += __shfl_xor(s[ni], 32);
    s2[ni] += __shfl_xor(s2[ni], 16); s2[ni] += __shfl_xor(s2[ni], 32);
  }
  if (quad == 0) {
    const int rh = w >> 1;
    #pragma unroll
    for (int ni = 0; ni < 4; ++ni) {
      const int col = wcol + ni*16 + mcol;
      ps[rh*256 + col]       = s[ni];
      ps[rh*256 + 128 + col] = s2[ni];
    }
  }
  __syncthreads();

  #pragma unroll
  for (int i = 0; i < 8; ++i) {
    const int u = i*256 + t;
    const int row = u >> 4, gg = u & 15;
    *(uint4*)(zhb + (size_t)(r0 + row)*128 + gg*8) =
        *(const uint4*)(S + row*128 + ((gg ^ (row & 15)) << 3));
  }
  atomicAdd(&midB[(blockIdx.x & 7)*256 + t], ps[t] + ps[256 + t]);
}

// ---------------- R8: conv2 layer3 + max on 32x32x16 MFMA ----------------
// R5-R7 post-mortem: coop fusion = no win (grid.sync + lockstep ate the traffic
// savings); split path restored. This kernel replaces the 16x16 l3max:
//  - wave w owns cols [w*256, w*256+256) as 8 ct tiles of 32; ALL 128 rows as
//    4 row-tile chains sharing each B fragment -> W3T read ONCE per block
//    (256 KB; device B-traffic halves to ~256 MB), dep-distance-4 MFMA chains.
//  - MFMA instr count halves (1024 x 32k-FLOP vs 2048 x 16k-FLOP).
//  - per-wave cols private -> direct pmax2 store, no pm buffer/combine.
//  - LDS 33 KB -> 4 blocks/CU x 256 CU = 1024 = one full round; VGPR ~110 < 128.
// Fragment layouts (family verified via the working 16x16 path + guide's measured
// C/D): A row=lane&31, k=(lane>>5)*8+i; B col=lane&31, same k; D col=lane&31,
// row=(reg&3)+8*(reg>>2)+4*(lane>>5).
__global__ __launch_bounds__(256, 4) void conv2_l3max_mfma32(
    const unsigned short* __restrict__ zhb, const float* __restrict__ midB,
    const float* __restrict__ g2, const float* __restrict__ be2,
    const unsigned short* __restrict__ W3T,
    float* __restrict__ pmax2) {
  __shared__ unsigned short As[128*128];   // 32 KB
  __shared__ float scl[128], shl[128];     // 1 KB
  const int rb = blockIdx.x;
  const int r0 = rb * 128;
  const int t = threadIdx.x;
  const int lane = t & 63, w = t >> 6;
  const float invR = 1.0f / (float)PK;

  if (t < 128) {
    float s = 0.0f, s2 = 0.0f;
    #pragma unroll
    for (int k = 0; k < 8; ++k) { s += midB[k*256 + t]; s2 += midB[k*256 + 128 + t]; }
    const float mu  = s * invR;
    const float var = s2 * invR - mu*mu;
    const float sc  = g2[t] * rsqrtf(var + 1e-5f);
    scl[t] = sc; shl[t] = be2[t] - mu*sc;
  }
  __syncthreads();

  {
    const int kb = t & 15, rr = t >> 4;
    float sc[8], sh[8];
    #pragma unroll
    for (int q = 0; q < 8; ++q) { sc[q] = scl[kb*8 + q]; sh[q] = shl[kb*8 + q]; }
    #pragma unroll
    for (int it = 0; it < 8; ++it) {
      const int r = rr + it*16;
      union { uint4 v; unsigned short s[8]; } in;
      in.v = *(const uint4*)(zhb + (size_t)(r0 + r)*128 + kb*8);
      union { unsigned short s[8]; uint4 v; } o;
      #pragma unroll
      for (int q = 0; q < 8; ++q)
        o.s[q] = f2h(fmaxf(h2f(in.s[q])*sc[q] + sh[q], 0.0f));
      *(uint4*)(As + r*128 + ((kb ^ (r & 7)) * 8)) = o.v;
    }
  }
  __syncthreads();

  const int row_in = lane & 31;     // row within a 32-row tile
  const int khalf  = lane >> 5;     // k-half selector

  #pragma unroll 1
  for (int cc = 0; cc < 8; ++cc) {
    const int ct = w*8 + cc;        // 32-col tile, private to this wave

    f32x16 a0 = {}, a1 = {}, a2 = {}, a3 = {};   // 4 row-tile chains

    #pragma unroll
    for (int ks = 0; ks < 8; ++ks) {
      const f16x8 bf = *(const f16x8*)(W3T + ((ct*8 + ks) << 9) + lane*8);
      const int g = ks*2 + khalf;   // k-group (k = g*8 + i)
      {
        const int row = row_in;
        const f16x8 a = *(const f16x8*)(As + row*128 + ((g ^ (row & 7)) * 8));
        a0 = __builtin_amdgcn_mfma_f32_32x32x16_f16(a, bf, a0, 0, 0, 0);
      }
      {
        const int row = 32 + row_in;
        const f16x8 a = *(const f16x8*)(As + row*128 + ((g ^ (row & 7)) * 8));
        a1 = __builtin_amdgcn_mfma_f32_32x32x16_f16(a, bf, a1, 0, 0, 0);
      }
      {
        const int row = 64 + row_in;
        const f16x8 a = *(const f16x8*)(As + row*128 + ((g ^ (row & 7)) * 8));
        a2 = __builtin_amdgcn_mfma_f32_32x32x16_f16(a, bf, a2, 0, 0, 0);
      }
      {
        const int row = 96 + row_in;
        const f16x8 a = *(const f16x8*)(As + row*128 + ((g ^ (row & 7)) * 8));
        a3 = __builtin_amdgcn_mfma_f32_32x32x16_f16(a, bf, a3, 0, 0, 0);
      }
    }

    // col-max over all 128 rows for col = ct*32 + (lane&31)
    float m = -INFINITY;
    #pragma unroll
    for (int r = 0; r < 16; ++r) {
      m = fmaxf(m, fmaxf(fmaxf(a0[r], a1[r]), fmaxf(a2[r], a3[r])));
    }
    m = fmaxf(m, __shfl_xor(m, 32));    // combine the two row-half lane groups
    if (lane < 32)
      pmax2[(size_t)rb*1024 + ct*32 + row_in] = m;
  }
}

// ---------------- fused per-graph max pool + final linear partials ----------------
__global__ __launch_bounds__(256) void poollin_kernel(const float* __restrict__ pmax2,
    const float* __restrict__ b3, const float* __restrict__ W,
    float* __restrict__ zpart) {
  __shared__ float gs[256];
  const int b = blockIdx.x >> 2, q = blockIdx.x & 3;
  const int t = threadIdx.x;
  const int c = q*256 + t;
  const float* p = pmax2 + (size_t)b*128*1024 + c;
  float m = -INFINITY;
  #pragma unroll 4
  for (int rb = 0; rb < 128; ++rb) m = fmaxf(m, p[(size_t)rb*1024]);
  gs[t] = m + b3[c];
  __syncthreads();
  const float* Wq = W + (size_t)q*256*256;
  float acc = 0.0f;
  for (int cc = 0; cc < 256; ++cc) acc += gs[cc] * Wq[cc*256 + t];
  zpart[blockIdx.x*256 + t] = acc;
}

// ---------------- final BN(8 rows) + relu ----------------
__global__ __launch_bounds__(256) void final_kernel(const float* __restrict__ zpart,
    const float* __restrict__ lb, const float* __restrict__ lg,
    const float* __restrict__ lbe, float* __restrict__ out) {
  const int o = threadIdx.x;
  float z[NB]; float s = 0.0f, s2 = 0.0f;
  #pragma unroll
  for (int b = 0; b < NB; ++b) {
    float v = lb[o];
    #pragma unroll
    for (int q = 0; q < 4; ++q) v += zpart[(b*4+q)*256 + o];
    z[b] = v; s += v; s2 += v*v;
  }
  const float mu  = s * 0.125f;
  const float var = s2 * 0.125f - mu*mu;
  const float inv = rsqrtf(var + 1e-5f);
  const float sc = lg[o]*inv, sh = lbe[o] - mu*sc;
  #pragma unroll
  for (int b = 0; b < NB; ++b) out[b*256 + o] = fmaxf(z[b]*sc + sh, 0.0f);
}

extern "C" void kernel_launch(void* const* d_in, const int* in_sizes, int n_in,
                              void* d_out, int out_size, void* d_ws, size_t ws_size,
                              hipStream_t stream) {
  const float* pos    = (const float*)d_in[0];
  const float* c1_W1  = (const float*)d_in[2];
  const float* c1_b1  = (const float*)d_in[3];
  const float* c1_g1  = (const float*)d_in[4];
  const float* c1_be1 = (const float*)d_in[5];
  const float* c1_W2  = (const float*)d_in[6];
  const float* c1_b2  = (const float*)d_in[7];
  const float* c2_W1  = (const float*)d_in[8];
  const float* c2_b1  = (const float*)d_in[9];
  const float* c2_g1  = (const float*)d_in[10];
  const float* c2_be1 = (const float*)d_in[11];
  const float* c2_W2  = (const float*)d_in[12];
  const float* c2_b2  = (const float*)d_in[13];
  const float* c2_g2  = (const float*)d_in[14];
  const float* c2_be2 = (const float*)d_in[15];
  const float* c2_W3  = (const float*)d_in[16];
  const float* c2_b3  = (const float*)d_in[17];
  const float* lin_W  = (const float*)d_in[18];
  const float* lin_b  = (const float*)d_in[19];
  const float* lin_g  = (const float*)d_in[20];
  const float* lin_be = (const float*)d_in[21];
  float* out = (float*)d_out;

  char* ws = (char*)d_ws;
  int*   idx     = (int*)  (ws + 0);                 // 512 KB
  float* rel     = (float*)(ws + 524288);            // 1.5 MB
  float* zpart   = (float*)(ws + 2097152 + 2048);    // 8 KB
  float* mid1    = (float*)(ws + 2164736);           // } zeroed by
  float* midA    = (float*)(ws + 2164736 + 4096);    // } wprep
  float* midB    = (float*)(ws + 2164736 + 8192);    // } block 140
  unsigned short* W2T   = (unsigned short*)(ws + 2295808);
  unsigned short* w1T   = (unsigned short*)(ws + 2312192);
  unsigned short* W2c1T = (unsigned short*)(ws + 2320384);
  unsigned short* z1h = (unsigned short*)(ws + 2426880);    // 16 MB
  unsigned short* zah = (unsigned short*)(ws + 2426880);    // reuses z1h region (dead)
  float* pmax2   = (float*)(ws + 2426880);                  // 4 MB (after zah dead)
  unsigned short* x1h = (unsigned short*)(ws + 35981312);   // 1 MB fp16
  unsigned short* zhb = (unsigned short*)(ws + 38078464);   // 33.5 MB
  unsigned short* W3T = (unsigned short*)(ws + 71632896);   // 256 KB

  wprep_kernel<<<141, 256, 0, stream>>>(c2_W3, c2_W2, c2_W1, c1_W2, W3T, W2T, w1T, W2c1T, mid1);
  knn_conv1_kernel<<<PTS/4, 256, 0, stream>>>(pos, c1_W1, c1_b1, idx, rel, z1h, mid1);
  conv1_l2max_mfma<<<PK/128, 256, 0, stream>>>(z1h, mid1, c1_g1, c1_be1, W2c1T, c1_b2, x1h);
  conv2_l1_mfma<<<PK/128, 256, 0, stream>>>(x1h, idx, rel, w1T, c2_W1, c2_b1, zah, midA);
  conv2_l2_mfma<<<PK/128, 256, 0, stream>>>(zah, midA, c2_g1, c2_be1, W2T, c2_b2, zhb, midB);
  conv2_l3max_mfma32<<<PK/128, 256, 0, stream>>>(zhb, midB, c2_g2, c2_be2, W3T, pmax2);
  poollin_kernel<<<NB*4, 256, 0, stream>>>(pmax2, c2_b3, lin_W, zpart);
  final_kernel<<<1, 256, 0, stream>>>(zpart, lin_b, lin_g, lin_be, out);
}

// Round 9
// 261.156 us; speedup vs baseline: 1.1969x; 1.1969x over previous
//
#include <hip/hip_runtime.h>
#include <math.h>

#define NB   8
#define NPTS 1024
#define PTS  8192      // NB*NPTS
#define KNN  16
#define PK   (PTS*KNN) // 131072

typedef __attribute__((ext_vector_type(8))) _Float16 f16x8;
typedef __attribute__((ext_vector_type(4))) float f32x4;
typedef __attribute__((ext_vector_type(16))) float f32x16;

__device__ __forceinline__ unsigned short f2h(float f) {
  _Float16 h = (_Float16)f;
  union { _Float16 h; unsigned short u; } c; c.h = h;
  return c.u;
}
__device__ __forceinline__ float h2f(unsigned short u) {
  union { unsigned short u; _Float16 h; } c; c.u = u;
  return (float)c.h;
}
__device__ __forceinline__ int lanerank(unsigned long long m) {
  return __builtin_amdgcn_mbcnt_hi((unsigned)(m >> 32),
         __builtin_amdgcn_mbcnt_lo((unsigned)m, 0));
}

// ---------------- kNN + conv1 layer1 fused: one WAVE per point ----------------
// R3 WIN: bitonic sort replaced by exact radix-SELECT; 54.7 -> <45 µs.
__global__ __launch_bounds__(256) void knn_conv1_kernel(const float* __restrict__ pos,
    const float* __restrict__ W1, const float* __restrict__ b1,
    int* __restrict__ idx, float* __restrict__ rel,
    unsigned short* __restrict__ z1h, float* __restrict__ mid1) {
  __shared__ float px[NPTS], py[NPTS], pz[NPTS];
  __shared__ float feat[4][KNN][6];
  __shared__ float ls[256], ls2[256];
  const int t = threadIdx.x;
  const int wv = t >> 6, lane = t & 63;
  const int b = blockIdx.x;
  const int graph = b >> 8;
  const int base = graph << 10;
  for (int j = t; j < NPTS; j += 256) {
    px[j] = pos[3*(base+j)];
    py[j] = pos[3*(base+j)+1];
    pz[j] = pos[3*(base+j)+2];
  }
  __syncthreads();

  const int il = ((b & 255) << 2) + wv;
  const int i  = base + il;
  const float pix = px[il], piy = py[il], piz = pz[il];
  const float sqi = pix*pix + piy*piy + piz*piz;

  unsigned key[16];
  #pragma unroll
  for (int q = 0; q < 16; ++q) {
    const int j = (q << 6) + lane;
    const float x = px[j], y = py[j], z = pz[j];
    const float sqj = x*x + y*y + z*z;
    const float dt  = pix*x + piy*y + piz*z;
    const float d   = sqi + sqj - 2.0f*dt;
    const unsigned db = __float_as_uint(d);
    key[q] = (db >> 31) ? ~db : (db | 0x80000000u);
  }

  unsigned V = 0;
  #pragma unroll 1
  for (int bb = 31; bb >= 0; --bb) {
    const unsigned test = V | (1u << bb);
    int cnt = 0;
    #pragma unroll
    for (int q = 0; q < 16; ++q)
      cnt += __popcll(__ballot(key[q] < test));
    if (cnt < 16) V = test;
  }

  int c = 0;
  #pragma unroll
  for (int q = 0; q < 16; ++q)
    c += __popcll(__ballot(key[q] < V));

  int p_lt = 0, p_eq = c;
  #pragma unroll 1
  for (int q = 0; q < 16; ++q) {
    const unsigned long long mlt = __ballot(key[q] < V);
    const unsigned long long meq = __ballot(key[q] == V);
    int slot = -1;
    if (key[q] < V) slot = p_lt + lanerank(mlt);
    else if (key[q] == V) {
      const int s = p_eq + lanerank(meq);
      if (s < 16) slot = s;
    }
    if (slot >= 0) {
      const int j = (q << 6) + lane;
      const int r = i*KNN + slot;
      const float rx = px[j] - pix, ry = py[j] - piy, rz = pz[j] - piz;
      idx[r] = base + j;
      rel[3*r] = rx; rel[3*r+1] = ry; rel[3*r+2] = rz;
      feat[wv][slot][0] = px[j]; feat[wv][slot][1] = py[j]; feat[wv][slot][2] = pz[j];
      feat[wv][slot][3] = rx;    feat[wv][slot][4] = ry;    feat[wv][slot][5] = rz;
    }
    p_lt += __popcll(mlt);
    p_eq += __popcll(meq);
  }

  float w[6];
  #pragma unroll
  for (int q = 0; q < 6; ++q) w[q] = W1[q*64 + lane];
  const float bbv = b1[lane];
  float s = 0.0f, s2 = 0.0f;
  #pragma unroll
  for (int k = 0; k < KNN; ++k) {
    float z = bbv;
    #pragma unroll
    for (int q = 0; q < 6; ++q) z += feat[wv][k][q]*w[q];
    z1h[(size_t)(i*KNN + k)*64 + lane] = f2h(z);
    s += z; s2 += z*z;
  }
  ls[t] = s; ls2[t] = s2;
  __syncthreads();
  if (t < 64) {
    float a  = ls[t] + ls[t+64] + ls[t+128] + ls[t+192];
    float a2 = ls2[t] + ls2[t+64] + ls2[t+128] + ls2[t+192];
    const int cp = (b & 7) * 128;
    atomicAdd(&mid1[cp + t], a);
    atomicAdd(&mid1[cp + 64 + t], a2);
  }
}

// ---------------- weight prep (block 140 zeroes mid1/midA/midB) ----------------
// R8: W3T emitted in 32x32x16 MFMA-FRAGMENT ORDER: fragment (ct,ks) = 1 KB, lane-major:
//   W3T[((ct*8+ks)<<9) + lane*8 + e] = W3[k = ks*16 + (lane>>5)*8 + e][n = ct*32 + (lane&31)]
__global__ __launch_bounds__(256) void wprep_kernel(const float* __restrict__ W3,
    const float* __restrict__ W2, const float* __restrict__ W1c2,
    const float* __restrict__ W2c1,
    unsigned short* __restrict__ W3T, unsigned short* __restrict__ W2T,
    unsigned short* __restrict__ w1T, unsigned short* __restrict__ W2c1T,
    float* __restrict__ mids) {
  const int b = blockIdx.x, t = threadIdx.x;
  if (b < 128) {
    const int k = b;
    const int ks = k >> 4, half = (k >> 3) & 1, e = k & 7;
    for (int n = t; n < 1024; n += 256) {
      const int ct = n >> 5, cc = n & 31;
      W3T[((ct*8 + ks) << 9) + (half*32 + cc)*8 + e] = f2h(W3[(size_t)k*1024 + n]);
    }
  } else if (b < 132) {
    for (int id = (b-128)*2048 + t; id < (b-127)*2048; id += 256) {
      const int n = id >> 6, k = id & 63;
      W2T[n*64 + k] = f2h(W2[k*128 + n]);
    }
  } else if (b < 136) {
    for (int id = (b-132)*1024 + t; id < (b-131)*1024; id += 256) {
      const int n = id >> 6, k = id & 63;
      w1T[n*64 + k] = f2h(W1c2[k*64 + n]);
    }
  } else if (b < 140) {
    for (int id = (b-136)*1024 + t; id < (b-135)*1024; id += 256) {
      const int n = id >> 6, k = id & 63;
      W2c1T[n*64 + k] = f2h(W2c1[k*64 + n]);
    }
  } else {
    for (int i2 = t; i2 < 4096; i2 += 256) mids[i2] = 0.0f;
  }
}

// ---------------- conv1 layer2 + max ----------------
__global__ __launch_bounds__(256) void conv1_l2max_mfma(
    const unsigned short* __restrict__ z1h, const float* __restrict__ mid1,
    const float* __restrict__ g1, const float* __restrict__ be1,
    const unsigned short* __restrict__ W2T, const float* __restrict__ b2,
    unsigned short* __restrict__ x1h) {
  __shared__ unsigned short As[128*64];
  __shared__ float scl[64], shl[64];
  const int r0 = blockIdx.x * 128;
  const int t = threadIdx.x;
  const int lane = t & 63, w = t >> 6;
  const int quad = lane >> 4, mcol = lane & 15;
  const float invR = 1.0f / (float)PK;

  if (t < 64) {
    float s = 0.0f, s2 = 0.0f;
    #pragma unroll
    for (int k = 0; k < 8; ++k) { s += mid1[k*128 + t]; s2 += mid1[k*128 + 64 + t]; }
    const float mu  = s * invR;
    const float var = s2 * invR - mu*mu;
    const float sc  = g1[t] * rsqrtf(var + 1e-5f);
    scl[t] = sc; shl[t] = be1[t] - mu*sc;
  }
  __syncthreads();

  {
    const int kb = t & 7, rr = t >> 3;
    float sc[8], sh[8];
    #pragma unroll
    for (int q = 0; q < 8; ++q) { sc[q] = scl[kb*8 + q]; sh[q] = shl[kb*8 + q]; }
    #pragma unroll
    for (int it = 0; it < 4; ++it) {
      const int r = rr + it*32;
      union { uint4 v; unsigned short s[8]; } in;
      in.v = *(const uint4*)(z1h + (size_t)(r0 + r)*64 + kb*8);
      union { unsigned short s[8]; uint4 v; } o;
      #pragma unroll
      for (int q = 0; q < 8; ++q)
        o.s[q] = f2h(fmaxf(h2f(in.s[q])*sc[q] + sh[q], 0.0f));
      *(uint4*)(As + r*64 + ((kb ^ (r & 7)) * 8)) = o.v;
    }
  }
  __syncthreads();

  const int wrow = (w >> 1) * 64;
  const int wncol = (w & 1) * 32;

  f32x4 acc[4][2];
  #pragma unroll
  for (int mi = 0; mi < 4; ++mi)
    #pragma unroll
    for (int ni = 0; ni < 2; ++ni)
      acc[mi][ni] = (f32x4){0.f, 0.f, 0.f, 0.f};

  #pragma unroll
  for (int ks = 0; ks < 2; ++ks) {
    f16x8 af[4], bfr[2];
    #pragma unroll
    for (int mi = 0; mi < 4; ++mi) {
      const int row = wrow + mi*16 + mcol;
      af[mi] = *(const f16x8*)(As + row*64 + (((ks*4 + quad) ^ (row & 7)) * 8));
    }
    #pragma unroll
    for (int ni = 0; ni < 2; ++ni) {
      const int nr = wncol + ni*16 + mcol;
      bfr[ni] = *(const f16x8*)(W2T + nr*64 + ks*32 + quad*8);
    }
    #pragma unroll
    for (int mi = 0; mi < 4; ++mi)
      #pragma unroll
      for (int ni = 0; ni < 2; ++ni)
        acc[mi][ni] = __builtin_amdgcn_mfma_f32_16x16x32_f16(af[mi], bfr[ni], acc[mi][ni], 0, 0, 0);
  }

  float bb[2];
  #pragma unroll
  for (int ni = 0; ni < 2; ++ni) bb[ni] = b2[wncol + ni*16 + mcol];
  #pragma unroll
  for (int mi = 0; mi < 4; ++mi) {
    const int p = blockIdx.x*8 + (w >> 1)*4 + mi;
    #pragma unroll
    for (int ni = 0; ni < 2; ++ni) {
      f32x4 a = acc[mi][ni];
      float m = fmaxf(fmaxf(a[0], a[1]), fmaxf(a[2], a[3]));
      m = fmaxf(m, __shfl_xor(m, 16));
      m = fmaxf(m, __shfl_xor(m, 32));
      if (quad == 0) x1h[(size_t)p*64 + wncol + ni*16 + mcol] = f2h(m + bb[ni]);
    }
  }
}

// ---------------- conv2 layer1: fp16 MFMA (gather + rank-3 rel fixup) ----------------
__global__ __launch_bounds__(256) void conv2_l1_mfma(
    const unsigned short* __restrict__ x1h, const int* __restrict__ idx,
    const float* __restrict__ rel, const unsigned short* __restrict__ w1T,
    const float* __restrict__ W1full, const float* __restrict__ b1,
    unsigned short* __restrict__ zah, float* __restrict__ midA) {
  __shared__ unsigned short S[128*64];
  __shared__ int   idxr[128];
  __shared__ float rl[128*3];
  __shared__ float ps[256];
  const int r0 = blockIdx.x * 128;
  const int t = threadIdx.x;
  const int lane = t & 63, w = t >> 6;
  const int quad = lane >> 4, mcol = lane & 15;

  if (t < 128) idxr[t] = idx[r0 + t];
  else if (t < 224) *(float4*)(rl + (t-128)*4) = *(const float4*)(rel + (size_t)r0*3 + (t-128)*4);
  __syncthreads();

  {
    const int kb = t & 7, rr = t >> 3;
    #pragma unroll
    for (int it = 0; it < 4; ++it) {
      const int r = rr + it*32;
      const int gj = idxr[r];
      const uint4 v = *(const uint4*)(x1h + (size_t)gj*64 + kb*8);
      *(uint4*)(S + r*64 + ((kb ^ (r & 7)) * 8)) = v;
    }
  }
  __syncthreads();

  const int wrow = (w >> 1) * 64;
  const int wcol = (w & 1) * 32;

  f16x8 af[2][4], bfr[2][2];
  #pragma unroll
  for (int ks = 0; ks < 2; ++ks)
    #pragma unroll
    for (int mi = 0; mi < 4; ++mi) {
      const int row = wrow + mi*16 + mcol;
      af[ks][mi] = *(const f16x8*)(S + row*64 + (((ks*4 + quad) ^ (row & 7)) * 8));
    }
  #pragma unroll
  for (int ks = 0; ks < 2; ++ks)
    #pragma unroll
    for (int ni = 0; ni < 2; ++ni) {
      const int nr = wcol + ni*16 + mcol;
      bfr[ks][ni] = *(const f16x8*)(w1T + nr*64 + ks*32 + quad*8);
    }

  f32x4 acc[4][2];
  #pragma unroll
  for (int mi = 0; mi < 4; ++mi)
    #pragma unroll
    for (int ni = 0; ni < 2; ++ni)
      acc[mi][ni] = (f32x4){0.f, 0.f, 0.f, 0.f};

  #pragma unroll
  for (int ks = 0; ks < 2; ++ks)
    #pragma unroll
    for (int mi = 0; mi < 4; ++mi)
      #pragma unroll
      for (int ni = 0; ni < 2; ++ni)
        acc[mi][ni] = __builtin_amdgcn_mfma_f32_16x16x32_f16(af[ks][mi], bfr[ks][ni], acc[mi][ni], 0, 0, 0);

  __syncthreads();

  float bb[2], wr0[2], wr1[2], wr2[2];
  #pragma unroll
  for (int ni = 0; ni < 2; ++ni) {
    const int col = wcol + ni*16 + mcol;
    bb[ni]  = b1[col];
    wr0[ni] = W1full[64*64 + col];
    wr1[ni] = W1full[65*64 + col];
    wr2[ni] = W1full[66*64 + col];
  }
  float s[2] = {0,0}, s2[2] = {0,0};
  #pragma unroll
  for (int mi = 0; mi < 4; ++mi) {
    #pragma unroll
    for (int j = 0; j < 4; ++j) {
      const int row = wrow + mi*16 + quad*4 + j;
      const float r0v = rl[row*3], r1v = rl[row*3+1], r2v = rl[row*3+2];
      #pragma unroll
      for (int ni = 0; ni < 2; ++ni) {
        const int col = wcol + ni*16 + mcol;
        const int g = col >> 3, o = col & 7;
        const float v = acc[mi][ni][j] + bb[ni] + r0v*wr0[ni] + r1v*wr1[ni] + r2v*wr2[ni];
        S[row*64 + ((g ^ (row & 7)) << 3) + o] = f2h(v);
        s[ni] += v; s2[ni] += v*v;
      }
    }
  }
  #pragma unroll
  for (int ni = 0; ni < 2; ++ni) {
    s[ni]  += __shfl_xor(s[ni], 16);  s[ni]  += __shfl_xor(s[ni], 32);
    s2[ni] += __shfl_xor(s2[ni], 16); s2[ni] += __shfl_xor(s2[ni], 32);
  }
  if (quad == 0) {
    const int rh = w >> 1;
    #pragma unroll
    for (int ni = 0; ni < 2; ++ni) {
      const int col = wcol + ni*16 + mcol;
      ps[rh*128 + col]      = s[ni];
      ps[rh*128 + 64 + col] = s2[ni];
    }
  }
  __syncthreads();

  #pragma unroll
  for (int i = 0; i < 4; ++i) {
    const int u = i*256 + t;
    const int row = u >> 3, gg = u & 7;
    *(uint4*)(zah + (size_t)(r0 + row)*64 + gg*8) =
        *(const uint4*)(S + row*64 + ((gg ^ (row & 7)) << 3));
  }
  if (t < 128) atomicAdd(&midA[(blockIdx.x & 7)*128 + t], ps[t] + ps[128 + t]);
}

// ---------------- conv2 layer2: fp16 MFMA; BN from 8-copy midA ----------------
__global__ __launch_bounds__(256) void conv2_l2_mfma(
    const unsigned short* __restrict__ zah, const float* __restrict__ midA,
    const float* __restrict__ g1, const float* __restrict__ be1,
    const unsigned short* __restrict__ W2T, const float* __restrict__ b2,
    unsigned short* __restrict__ zhb, float* __restrict__ midB) {
  __shared__ unsigned short S[128*128];
  __shared__ float ps[512];
  __shared__ float scl[64], shl[64];
  const int r0 = blockIdx.x * 128;
  const int t = threadIdx.x;
  const int lane = t & 63, w = t >> 6;
  const int quad = lane >> 4, mcol = lane & 15;
  const float invR = 1.0f / (float)PK;

  if (t < 64) {
    float s = 0.0f, s2 = 0.0f;
    #pragma unroll
    for (int k = 0; k < 8; ++k) { s += midA[k*128 + t]; s2 += midA[k*128 + 64 + t]; }
    const float mu  = s * invR;
    const float var = s2 * invR - mu*mu;
    const float sc  = g1[t] * rsqrtf(var + 1e-5f);
    scl[t] = sc; shl[t] = be1[t] - mu*sc;
  }
  __syncthreads();

  {
    const int kb = t & 7, rr = t >> 3;
    float sc[8], sh[8];
    #pragma unroll
    for (int q = 0; q < 8; ++q) { sc[q] = scl[kb*8 + q]; sh[q] = shl[kb*8 + q]; }
    #pragma unroll
    for (int it = 0; it < 4; ++it) {
      const int r = rr + it*32;
      union { uint4 v; unsigned short s[8]; } in;
      in.v = *(const uint4*)(zah + (size_t)(r0 + r)*64 + kb*8);
      union { unsigned short s[8]; uint4 v; } o;
      #pragma unroll
      for (int q = 0; q < 8; ++q)
        o.s[q] = f2h(fmaxf(h2f(in.s[q])*sc[q] + sh[q], 0.0f));
      *(uint4*)(S + r*64 + ((kb ^ (r & 7)) * 8)) = o.v;
    }
  }
  __syncthreads();

  const int wrow = (w >> 1) * 64;
  const int wcol = (w & 1) * 64;

  f16x8 af[2][4], bfr[2][4];
  #pragma unroll
  for (int ks = 0; ks < 2; ++ks)
    #pragma unroll
    for (int mi = 0; mi < 4; ++mi) {
      const int row = wrow + mi*16 + mcol;
      af[ks][mi] = *(const f16x8*)(S + row*64 + (((ks*4 + quad) ^ (row & 7)) * 8));
    }
  #pragma unroll
  for (int ks = 0; ks < 2; ++ks)
    #pragma unroll
    for (int ni = 0; ni < 4; ++ni) {
      const int nr = wcol + ni*16 + mcol;
      bfr[ks][ni] = *(const f16x8*)(W2T + nr*64 + ks*32 + quad*8);
    }

  f32x4 acc[4][4];
  #pragma unroll
  for (int mi = 0; mi < 4; ++mi)
    #pragma unroll
    for (int ni = 0; ni < 4; ++ni)
      acc[mi][ni] = (f32x4){0.f, 0.f, 0.f, 0.f};

  #pragma unroll
  for (int ks = 0; ks < 2; ++ks)
    #pragma unroll
    for (int mi = 0; mi < 4; ++mi)
      #pragma unroll
      for (int ni = 0; ni < 4; ++ni)
        acc[mi][ni] = __builtin_amdgcn_mfma_f32_16x16x32_f16(af[ks][mi], bfr[ks][ni], acc[mi][ni], 0, 0, 0);

  __syncthreads();

  float bb[4];
  #pragma unroll
  for (int ni = 0; ni < 4; ++ni) bb[ni] = b2[wcol + ni*16 + mcol];
  float s[4] = {0,0,0,0}, s2[4] = {0,0,0,0};
  #pragma unroll
  for (int mi = 0; mi < 4; ++mi) {
    #pragma unroll
    for (int ni = 0; ni < 4; ++ni) {
      const int col = wcol + ni*16 + mcol;
      const int g = col >> 3, o = col & 7;
      #pragma unroll
      for (int j = 0; j < 4; ++j) {
        const int row = wrow + mi*16 + quad*4 + j;
        const float v = acc[mi][ni][j] + bb[ni];
        S[row*128 + ((g ^ (row & 15)) << 3) + o] = f2h(v);
        s[ni] += v; s2[ni] += v*v;
      }
    }
  }
  #pragma unroll
  for (int ni = 0; ni < 4; ++ni) {
    s[ni]  += __shfl_xor(s[ni], 16);  s[ni]  += __shfl_xor(s[ni], 32);
    s2[ni] += __shfl_xor(s2[ni], 16); s2[ni] += __shfl_xor(s2[ni], 32);
  }
  if (quad == 0) {
    const int rh = w >> 1;
    #pragma unroll
    for (int ni = 0; ni < 4; ++ni) {
      const int col = wcol + ni*16 + mcol;
      ps[rh*256 + col]       = s[ni];
      ps[rh*256 + 128 + col] = s2[ni];
    }
  }
  __syncthreads();

  #pragma unroll
  for (int i = 0; i < 8; ++i) {
    const int u = i*256 + t;
    const int row = u >> 4, gg = u & 15;
    *(uint4*)(zhb + (size_t)(r0 + row)*128 + gg*8) =
        *(const uint4*)(S + row*128 + ((gg ^ (row & 15)) << 3));
  }
  atomicAdd(&midB[(blockIdx.x & 7)*256 + t], ps[t] + ps[256 + t]);
}

// ---------------- R9: conv2 layer3 + max, 32x32x16, block-lockstep B sweep ----------------
// R8 post-mortem: cols-per-wave gave each wave a PRIVATE 64KB B-stream -> zero L2
// reuse, FETCH 344 MB (= full logical B volume), 116 µs. R2's measured 26.7 MB FETCH
// proves phase-coherent shared sweeps DO get cached. R9 inverts ownership:
//  - wave w owns ROWS [32w,32w+32): A-frags = 8 x f16x8 = 32 VGPR, loaded from LDS
//    ONCE per block (8 ds_reads/wave vs R8's 256), reused across all 32 col-tiles.
//  - ALL waves/blocks sweep cols ct=0..31 in the SAME order: every wave of every
//    block reads the SAME W3T fragment at ~the same time -> L1 merge + L2 hits.
//  - ct processed in groups of 4: four independent acc chains (64 AGPR), dep
//    distance 4 >= MFMA latency.
//  - After A-frag loads + barrier, As is DEAD -> pm[4][1024] (16 KB) overlays it;
//    LDS stays 33 KB -> 4 blocks/CU.
// Fragment layouts identical to R8 (validated: R8 passed with absmax 0.0273).
__global__ __launch_bounds__(256, 4) void conv2_l3max_mfma32(
    const unsigned short* __restrict__ zhb, const float* __restrict__ midB,
    const float* __restrict__ g2, const float* __restrict__ be2,
    const unsigned short* __restrict__ W3T,
    float* __restrict__ pmax2) {
  __shared__ unsigned short As[128*128];   // 32 KB; pm overlays after A-frags read
  __shared__ float scl[128], shl[128];     // 1 KB
  float* const pm = (float*)As;            // [4 waves][1024 cols] = 16 KB
  const int rb = blockIdx.x;
  const int r0 = rb * 128;
  const int t = threadIdx.x;
  const int lane = t & 63, w = t >> 6;
  const float invR = 1.0f / (float)PK;

  if (t < 128) {
    float s = 0.0f, s2 = 0.0f;
    #pragma unroll
    for (int k = 0; k < 8; ++k) { s += midB[k*256 + t]; s2 += midB[k*256 + 128 + t]; }
    const float mu  = s * invR;
    const float var = s2 * invR - mu*mu;
    const float sc  = g2[t] * rsqrtf(var + 1e-5f);
    scl[t] = sc; shl[t] = be2[t] - mu*sc;
  }
  __syncthreads();

  {
    const int kb = t & 15, rr = t >> 4;
    float sc[8], sh[8];
    #pragma unroll
    for (int q = 0; q < 8; ++q) { sc[q] = scl[kb*8 + q]; sh[q] = shl[kb*8 + q]; }
    #pragma unroll
    for (int it = 0; it < 8; ++it) {
      const int r = rr + it*16;
      union { uint4 v; unsigned short s[8]; } in;
      in.v = *(const uint4*)(zhb + (size_t)(r0 + r)*128 + kb*8);
      union { unsigned short s[8]; uint4 v; } o;
      #pragma unroll
      for (int q = 0; q < 8; ++q)
        o.s[q] = f2h(fmaxf(h2f(in.s[q])*sc[q] + sh[q], 0.0f));
      *(uint4*)(As + r*128 + ((kb ^ (r & 7)) * 8)) = o.v;
    }
  }
  __syncthreads();

  // ---- A fragments: wave w's 32 rows, all 8 k-groups -> 32 VGPRs, read ONCE ----
  const int row = w*32 + (lane & 31);
  const int khalf = lane >> 5;
  f16x8 af[8];
  #pragma unroll
  for (int ks = 0; ks < 8; ++ks) {
    const int g = ks*2 + khalf;
    af[ks] = *(const f16x8*)(As + row*128 + ((g ^ (row & 7)) * 8));
  }
  __syncthreads();   // all A-frags in registers -> As dead -> pm writable

  // ---- col sweep: identical order for every wave and block (L2-coherent) ----
  #pragma unroll 1
  for (int cg = 0; cg < 8; ++cg) {
    f32x16 a0 = {}, a1 = {}, a2 = {}, a3 = {};   // 4 col-tile chains (ct = cg*4+c)
    #pragma unroll
    for (int ks = 0; ks < 8; ++ks) {
      const unsigned short* bp = W3T + (((cg*4)*8 + ks) << 9) + lane*8;
      const f16x8 b0 = *(const f16x8*)(bp);
      const f16x8 b1 = *(const f16x8*)(bp + (8 << 9));
      const f16x8 b2 = *(const f16x8*)(bp + (16 << 9));
      const f16x8 b3 = *(const f16x8*)(bp + (24 << 9));
      a0 = __builtin_amdgcn_mfma_f32_32x32x16_f16(af[ks], b0, a0, 0, 0, 0);
      a1 = __builtin_amdgcn_mfma_f32_32x32x16_f16(af[ks], b1, a1, 0, 0, 0);
      a2 = __builtin_amdgcn_mfma_f32_32x32x16_f16(af[ks], b2, a2, 0, 0, 0);
      a3 = __builtin_amdgcn_mfma_f32_32x32x16_f16(af[ks], b3, a3, 0, 0, 0);
    }

    float m0 = -INFINITY, m1 = -INFINITY, m2 = -INFINITY, m3 = -INFINITY;
    #pragma unroll
    for (int r = 0; r < 16; ++r) {
      m0 = fmaxf(m0, a0[r]); m1 = fmaxf(m1, a1[r]);
      m2 = fmaxf(m2, a2[r]); m3 = fmaxf(m3, a3[r]);
    }
    m0 = fmaxf(m0, __shfl_xor(m0, 32));
    m1 = fmaxf(m1, __shfl_xor(m1, 32));
    m2 = fmaxf(m2, __shfl_xor(m2, 32));
    m3 = fmaxf(m3, __shfl_xor(m3, 32));
    if (lane < 32) {
      pm[w*1024 + (cg*4 + 0)*32 + lane] = m0;
      pm[w*1024 + (cg*4 + 1)*32 + lane] = m1;
      pm[w*1024 + (cg*4 + 2)*32 + lane] = m2;
      pm[w*1024 + (cg*4 + 3)*32 + lane] = m3;
    }
  }
  __syncthreads();

  #pragma unroll
  for (int i = 0; i < 4; ++i) {
    const int c = i*256 + t;
    pmax2[(size_t)rb*1024 + c] =
        fmaxf(fmaxf(pm[c], pm[1024 + c]), fmaxf(pm[2048 + c], pm[3072 + c]));
  }
}

// ---------------- fused per-graph max pool + final linear partials ----------------
__global__ __launch_bounds__(256) void poollin_kernel(const float* __restrict__ pmax2,
    const float* __restrict__ b3, const float* __restrict__ W,
    float* __restrict__ zpart) {
  __shared__ float gs[256];
  const int b = blockIdx.x >> 2, q = blockIdx.x & 3;
  const int t = threadIdx.x;
  const int c = q*256 + t;
  const float* p = pmax2 + (size_t)b*128*1024 + c;
  float m = -INFINITY;
  #pragma unroll 4
  for (int rb = 0; rb < 128; ++rb) m = fmaxf(m, p[(size_t)rb*1024]);
  gs[t] = m + b3[c];
  __syncthreads();
  const float* Wq = W + (size_t)q*256*256;
  float acc = 0.0f;
  for (int cc = 0; cc < 256; ++cc) acc += gs[cc] * Wq[cc*256 + t];
  zpart[blockIdx.x*256 + t] = acc;
}

// ---------------- final BN(8 rows) + relu ----------------
__global__ __launch_bounds__(256) void final_kernel(const float* __restrict__ zpart,
    const float* __restrict__ lb, const float* __restrict__ lg,
    const float* __restrict__ lbe, float* __restrict__ out) {
  const int o = threadIdx.x;
  float z[NB]; float s = 0.0f, s2 = 0.0f;
  #pragma unroll
  for (int b = 0; b < NB; ++b) {
    float v = lb[o];
    #pragma unroll
    for (int q = 0; q < 4; ++q) v += zpart[(b*4+q)*256 + o];
    z[b] = v; s += v; s2 += v*v;
  }
  const float mu  = s * 0.125f;
  const float var = s2 * 0.125f - mu*mu;
  const float inv = rsqrtf(var + 1e-5f);
  const float sc = lg[o]*inv, sh = lbe[o] - mu*sc;
  #pragma unroll
  for (int b = 0; b < NB; ++b) out[b*256 + o] = fmaxf(z[b]*sc + sh, 0.0f);
}

extern "C" void kernel_launch(void* const* d_in, const int* in_sizes, int n_in,
                              void* d_out, int out_size, void* d_ws, size_t ws_size,
                              hipStream_t stream) {
  const float* pos    = (const float*)d_in[0];
  const float* c1_W1  = (const float*)d_in[2];
  const float* c1_b1  = (const float*)d_in[3];
  const float* c1_g1  = (const float*)d_in[4];
  const float* c1_be1 = (const float*)d_in[5];
  const float* c1_W2  = (const float*)d_in[6];
  const float* c1_b2  = (const float*)d_in[7];
  const float* c2_W1  = (const float*)d_in[8];
  const float* c2_b1  = (const float*)d_in[9];
  const float* c2_g1  = (const float*)d_in[10];
  const float* c2_be1 = (const float*)d_in[11];
  const float* c2_W2  = (const float*)d_in[12];
  const float* c2_b2  = (const float*)d_in[13];
  const float* c2_g2  = (const float*)d_in[14];
  const float* c2_be2 = (const float*)d_in[15];
  const float* c2_W3  = (const float*)d_in[16];
  const float* c2_b3  = (const float*)d_in[17];
  const float* lin_W  = (const float*)d_in[18];
  const float* lin_b  = (const float*)d_in[19];
  const float* lin_g  = (const float*)d_in[20];
  const float* lin_be = (const float*)d_in[21];
  float* out = (float*)d_out;

  char* ws = (char*)d_ws;
  int*   idx     = (int*)  (ws + 0);                 // 512 KB
  float* rel     = (float*)(ws + 524288);            // 1.5 MB
  float* zpart   = (float*)(ws + 2097152 + 2048);    // 8 KB
  float* mid1    = (float*)(ws + 2164736);           // } zeroed by
  float* midA    = (float*)(ws + 2164736 + 4096);    // } wprep
  float* midB    = (float*)(ws + 2164736 + 8192);    // } block 140
  unsigned short* W2T   = (unsigned short*)(ws + 2295808);
  unsigned short* w1T   = (unsigned short*)(ws + 2312192);
  unsigned short* W2c1T = (unsigned short*)(ws + 2320384);
  unsigned short* z1h = (unsigned short*)(ws + 2426880);    // 16 MB
  unsigned short* zah = (unsigned short*)(ws + 2426880);    // reuses z1h region (dead)
  float* pmax2   = (float*)(ws + 2426880);                  // 4 MB (after zah dead)
  unsigned short* x1h = (unsigned short*)(ws + 35981312);   // 1 MB fp16
  unsigned short* zhb = (unsigned short*)(ws + 38078464);   // 33.5 MB
  unsigned short* W3T = (unsigned short*)(ws + 71632896);   // 256 KB

  wprep_kernel<<<141, 256, 0, stream>>>(c2_W3, c2_W2, c2_W1, c1_W2, W3T, W2T, w1T, W2c1T, mid1);
  knn_conv1_kernel<<<PTS/4, 256, 0, stream>>>(pos, c1_W1, c1_b1, idx, rel, z1h, mid1);
  conv1_l2max_mfma<<<PK/128, 256, 0, stream>>>(z1h, mid1, c1_g1, c1_be1, W2c1T, c1_b2, x1h);
  conv2_l1_mfma<<<PK/128, 256, 0, stream>>>(x1h, idx, rel, w1T, c2_W1, c2_b1, zah, midA);
  conv2_l2_mfma<<<PK/128, 256, 0, stream>>>(zah, midA, c2_g1, c2_be1, W2T, c2_b2, zhb, midB);
  conv2_l3max_mfma32<<<PK/128, 256, 0, stream>>>(zhb, midB, c2_g2, c2_be2, W3T, pmax2);
  poollin_kernel<<<NB*4, 256, 0, stream>>>(pmax2, c2_b3, lin_W, zpart);
  final_kernel<<<1, 256, 0, stream>>>(zpart, lin_b, lin_g, lin_be, out);
}

// Round 10
// 239.207 us; speedup vs baseline: 1.3067x; 1.0918x over previous
//
#include <hip/hip_runtime.h>
#include <math.h>

#define NB   8
#define NPTS 1024
#define PTS  8192      // NB*NPTS
#define KNN  16
#define PK   (PTS*KNN) // 131072

typedef __attribute__((ext_vector_type(8))) _Float16 f16x8;
typedef __attribute__((ext_vector_type(4))) float f32x4;
typedef __attribute__((ext_vector_type(16))) float f32x16;

__device__ __forceinline__ unsigned short f2h(float f) {
  _Float16 h = (_Float16)f;
  union { _Float16 h; unsigned short u; } c; c.h = h;
  return c.u;
}
__device__ __forceinline__ float h2f(unsigned short u) {
  union { unsigned short u; _Float16 h; } c; c.u = u;
  return (float)c.h;
}
__device__ __forceinline__ int lanerank(unsigned long long m) {
  return __builtin_amdgcn_mbcnt_hi((unsigned)(m >> 32),
         __builtin_amdgcn_mbcnt_lo((unsigned)m, 0));
}

// ---------------- kNN + conv1 layer1 fused: one WAVE per point ----------------
// R3 WIN: bitonic sort replaced by exact radix-SELECT; 54.7 -> <45 µs.
__global__ __launch_bounds__(256) void knn_conv1_kernel(const float* __restrict__ pos,
    const float* __restrict__ W1, const float* __restrict__ b1,
    int* __restrict__ idx, float* __restrict__ rel,
    unsigned short* __restrict__ z1h, float* __restrict__ mid1) {
  __shared__ float px[NPTS], py[NPTS], pz[NPTS];
  __shared__ float feat[4][KNN][6];
  __shared__ float ls[256], ls2[256];
  const int t = threadIdx.x;
  const int wv = t >> 6, lane = t & 63;
  const int b = blockIdx.x;
  const int graph = b >> 8;
  const int base = graph << 10;
  for (int j = t; j < NPTS; j += 256) {
    px[j] = pos[3*(base+j)];
    py[j] = pos[3*(base+j)+1];
    pz[j] = pos[3*(base+j)+2];
  }
  __syncthreads();

  const int il = ((b & 255) << 2) + wv;
  const int i  = base + il;
  const float pix = px[il], piy = py[il], piz = pz[il];
  const float sqi = pix*pix + piy*piy + piz*piz;

  unsigned key[16];
  #pragma unroll
  for (int q = 0; q < 16; ++q) {
    const int j = (q << 6) + lane;
    const float x = px[j], y = py[j], z = pz[j];
    const float sqj = x*x + y*y + z*z;
    const float dt  = pix*x + piy*y + piz*z;
    const float d   = sqi + sqj - 2.0f*dt;
    const unsigned db = __float_as_uint(d);
    key[q] = (db >> 31) ? ~db : (db | 0x80000000u);
  }

  unsigned V = 0;
  #pragma unroll 1
  for (int bb = 31; bb >= 0; --bb) {
    const unsigned test = V | (1u << bb);
    int cnt = 0;
    #pragma unroll
    for (int q = 0; q < 16; ++q)
      cnt += __popcll(__ballot(key[q] < test));
    if (cnt < 16) V = test;
  }

  int c = 0;
  #pragma unroll
  for (int q = 0; q < 16; ++q)
    c += __popcll(__ballot(key[q] < V));

  int p_lt = 0, p_eq = c;
  #pragma unroll 1
  for (int q = 0; q < 16; ++q) {
    const unsigned long long mlt = __ballot(key[q] < V);
    const unsigned long long meq = __ballot(key[q] == V);
    int slot = -1;
    if (key[q] < V) slot = p_lt + lanerank(mlt);
    else if (key[q] == V) {
      const int s = p_eq + lanerank(meq);
      if (s < 16) slot = s;
    }
    if (slot >= 0) {
      const int j = (q << 6) + lane;
      const int r = i*KNN + slot;
      const float rx = px[j] - pix, ry = py[j] - piy, rz = pz[j] - piz;
      idx[r] = base + j;
      rel[3*r] = rx; rel[3*r+1] = ry; rel[3*r+2] = rz;
      feat[wv][slot][0] = px[j]; feat[wv][slot][1] = py[j]; feat[wv][slot][2] = pz[j];
      feat[wv][slot][3] = rx;    feat[wv][slot][4] = ry;    feat[wv][slot][5] = rz;
    }
    p_lt += __popcll(mlt);
    p_eq += __popcll(meq);
  }

  float w[6];
  #pragma unroll
  for (int q = 0; q < 6; ++q) w[q] = W1[q*64 + lane];
  const float bbv = b1[lane];
  float s = 0.0f, s2 = 0.0f;
  #pragma unroll
  for (int k = 0; k < KNN; ++k) {
    float z = bbv;
    #pragma unroll
    for (int q = 0; q < 6; ++q) z += feat[wv][k][q]*w[q];
    z1h[(size_t)(i*KNN + k)*64 + lane] = f2h(z);
    s += z; s2 += z*z;
  }
  ls[t] = s; ls2[t] = s2;
  __syncthreads();
  if (t < 64) {
    float a  = ls[t] + ls[t+64] + ls[t+128] + ls[t+192];
    float a2 = ls2[t] + ls2[t+64] + ls2[t+128] + ls2[t+192];
    const int cp = (b & 7) * 128;
    atomicAdd(&mid1[cp + t], a);
    atomicAdd(&mid1[cp + 64 + t], a2);
  }
}

// ---------------- weight prep (block 140 zeroes mid1/midA/midB) ----------------
// R8: W3T emitted in 32x32x16 MFMA-FRAGMENT ORDER: fragment (ct,ks) = 1 KB, lane-major:
//   W3T[((ct*8+ks)<<9) + lane*8 + e] = W3[k = ks*16 + (lane>>5)*8 + e][n = ct*32 + (lane&31)]
__global__ __launch_bounds__(256) void wprep_kernel(const float* __restrict__ W3,
    const float* __restrict__ W2, const float* __restrict__ W1c2,
    const float* __restrict__ W2c1,
    unsigned short* __restrict__ W3T, unsigned short* __restrict__ W2T,
    unsigned short* __restrict__ w1T, unsigned short* __restrict__ W2c1T,
    float* __restrict__ mids) {
  const int b = blockIdx.x, t = threadIdx.x;
  if (b < 128) {
    const int k = b;
    const int ks = k >> 4, half = (k >> 3) & 1, e = k & 7;
    for (int n = t; n < 1024; n += 256) {
      const int ct = n >> 5, cc = n & 31;
      W3T[((ct*8 + ks) << 9) + (half*32 + cc)*8 + e] = f2h(W3[(size_t)k*1024 + n]);
    }
  } else if (b < 132) {
    for (int id = (b-128)*2048 + t; id < (b-127)*2048; id += 256) {
      const int n = id >> 6, k = id & 63;
      W2T[n*64 + k] = f2h(W2[k*128 + n]);
    }
  } else if (b < 136) {
    for (int id = (b-132)*1024 + t; id < (b-131)*1024; id += 256) {
      const int n = id >> 6, k = id & 63;
      w1T[n*64 + k] = f2h(W1c2[k*64 + n]);
    }
  } else if (b < 140) {
    for (int id = (b-136)*1024 + t; id < (b-135)*1024; id += 256) {
      const int n = id >> 6, k = id & 63;
      W2c1T[n*64 + k] = f2h(W2c1[k*64 + n]);
    }
  } else {
    for (int i2 = t; i2 < 4096; i2 += 256) mids[i2] = 0.0f;
  }
}

// ---------------- conv1 layer2 + max ----------------
__global__ __launch_bounds__(256) void conv1_l2max_mfma(
    const unsigned short* __restrict__ z1h, const float* __restrict__ mid1,
    const float* __restrict__ g1, const float* __restrict__ be1,
    const unsigned short* __restrict__ W2T, const float* __restrict__ b2,
    unsigned short* __restrict__ x1h) {
  __shared__ unsigned short As[128*64];
  __shared__ float scl[64], shl[64];
  const int r0 = blockIdx.x * 128;
  const int t = threadIdx.x;
  const int lane = t & 63, w = t >> 6;
  const int quad = lane >> 4, mcol = lane & 15;
  const float invR = 1.0f / (float)PK;

  if (t < 64) {
    float s = 0.0f, s2 = 0.0f;
    #pragma unroll
    for (int k = 0; k < 8; ++k) { s += mid1[k*128 + t]; s2 += mid1[k*128 + 64 + t]; }
    const float mu  = s * invR;
    const float var = s2 * invR - mu*mu;
    const float sc  = g1[t] * rsqrtf(var + 1e-5f);
    scl[t] = sc; shl[t] = be1[t] - mu*sc;
  }
  __syncthreads();

  {
    const int kb = t & 7, rr = t >> 3;
    float sc[8], sh[8];
    #pragma unroll
    for (int q = 0; q < 8; ++q) { sc[q] = scl[kb*8 + q]; sh[q] = shl[kb*8 + q]; }
    #pragma unroll
    for (int it = 0; it < 4; ++it) {
      const int r = rr + it*32;
      union { uint4 v; unsigned short s[8]; } in;
      in.v = *(const uint4*)(z1h + (size_t)(r0 + r)*64 + kb*8);
      union { unsigned short s[8]; uint4 v; } o;
      #pragma unroll
      for (int q = 0; q < 8; ++q)
        o.s[q] = f2h(fmaxf(h2f(in.s[q])*sc[q] + sh[q], 0.0f));
      *(uint4*)(As + r*64 + ((kb ^ (r & 7)) * 8)) = o.v;
    }
  }
  __syncthreads();

  const int wrow = (w >> 1) * 64;
  const int wncol = (w & 1) * 32;

  f32x4 acc[4][2];
  #pragma unroll
  for (int mi = 0; mi < 4; ++mi)
    #pragma unroll
    for (int ni = 0; ni < 2; ++ni)
      acc[mi][ni] = (f32x4){0.f, 0.f, 0.f, 0.f};

  #pragma unroll
  for (int ks = 0; ks < 2; ++ks) {
    f16x8 af[4], bfr[2];
    #pragma unroll
    for (int mi = 0; mi < 4; ++mi) {
      const int row = wrow + mi*16 + mcol;
      af[mi] = *(const f16x8*)(As + row*64 + (((ks*4 + quad) ^ (row & 7)) * 8));
    }
    #pragma unroll
    for (int ni = 0; ni < 2; ++ni) {
      const int nr = wncol + ni*16 + mcol;
      bfr[ni] = *(const f16x8*)(W2T + nr*64 + ks*32 + quad*8);
    }
    #pragma unroll
    for (int mi = 0; mi < 4; ++mi)
      #pragma unroll
      for (int ni = 0; ni < 2; ++ni)
        acc[mi][ni] = __builtin_amdgcn_mfma_f32_16x16x32_f16(af[mi], bfr[ni], acc[mi][ni], 0, 0, 0);
  }

  float bb[2];
  #pragma unroll
  for (int ni = 0; ni < 2; ++ni) bb[ni] = b2[wncol + ni*16 + mcol];
  #pragma unroll
  for (int mi = 0; mi < 4; ++mi) {
    const int p = blockIdx.x*8 + (w >> 1)*4 + mi;
    #pragma unroll
    for (int ni = 0; ni < 2; ++ni) {
      f32x4 a = acc[mi][ni];
      float m = fmaxf(fmaxf(a[0], a[1]), fmaxf(a[2], a[3]));
      m = fmaxf(m, __shfl_xor(m, 16));
      m = fmaxf(m, __shfl_xor(m, 32));
      if (quad == 0) x1h[(size_t)p*64 + wncol + ni*16 + mcol] = f2h(m + bb[ni]);
    }
  }
}

// ---------------- conv2 layer1: fp16 MFMA (gather + rank-3 rel fixup) ----------------
__global__ __launch_bounds__(256) void conv2_l1_mfma(
    const unsigned short* __restrict__ x1h, const int* __restrict__ idx,
    const float* __restrict__ rel, const unsigned short* __restrict__ w1T,
    const float* __restrict__ W1full, const float* __restrict__ b1,
    unsigned short* __restrict__ zah, float* __restrict__ midA) {
  __shared__ unsigned short S[128*64];
  __shared__ int   idxr[128];
  __shared__ float rl[128*3];
  __shared__ float ps[256];
  const int r0 = blockIdx.x * 128;
  const int t = threadIdx.x;
  const int lane = t & 63, w = t >> 6;
  const int quad = lane >> 4, mcol = lane & 15;

  if (t < 128) idxr[t] = idx[r0 + t];
  else if (t < 224) *(float4*)(rl + (t-128)*4) = *(const float4*)(rel + (size_t)r0*3 + (t-128)*4);
  __syncthreads();

  {
    const int kb = t & 7, rr = t >> 3;
    #pragma unroll
    for (int it = 0; it < 4; ++it) {
      const int r = rr + it*32;
      const int gj = idxr[r];
      const uint4 v = *(const uint4*)(x1h + (size_t)gj*64 + kb*8);
      *(uint4*)(S + r*64 + ((kb ^ (r & 7)) * 8)) = v;
    }
  }
  __syncthreads();

  const int wrow = (w >> 1) * 64;
  const int wcol = (w & 1) * 32;

  f16x8 af[2][4], bfr[2][2];
  #pragma unroll
  for (int ks = 0; ks < 2; ++ks)
    #pragma unroll
    for (int mi = 0; mi < 4; ++mi) {
      const int row = wrow + mi*16 + mcol;
      af[ks][mi] = *(const f16x8*)(S + row*64 + (((ks*4 + quad) ^ (row & 7)) * 8));
    }
  #pragma unroll
  for (int ks = 0; ks < 2; ++ks)
    #pragma unroll
    for (int ni = 0; ni < 2; ++ni) {
      const int nr = wcol + ni*16 + mcol;
      bfr[ks][ni] = *(const f16x8*)(w1T + nr*64 + ks*32 + quad*8);
    }

  f32x4 acc[4][2];
  #pragma unroll
  for (int mi = 0; mi < 4; ++mi)
    #pragma unroll
    for (int ni = 0; ni < 2; ++ni)
      acc[mi][ni] = (f32x4){0.f, 0.f, 0.f, 0.f};

  #pragma unroll
  for (int ks = 0; ks < 2; ++ks)
    #pragma unroll
    for (int mi = 0; mi < 4; ++mi)
      #pragma unroll
      for (int ni = 0; ni < 2; ++ni)
        acc[mi][ni] = __builtin_amdgcn_mfma_f32_16x16x32_f16(af[ks][mi], bfr[ks][ni], acc[mi][ni], 0, 0, 0);

  __syncthreads();

  float bb[2], wr0[2], wr1[2], wr2[2];
  #pragma unroll
  for (int ni = 0; ni < 2; ++ni) {
    const int col = wcol + ni*16 + mcol;
    bb[ni]  = b1[col];
    wr0[ni] = W1full[64*64 + col];
    wr1[ni] = W1full[65*64 + col];
    wr2[ni] = W1full[66*64 + col];
  }
  float s[2] = {0,0}, s2[2] = {0,0};
  #pragma unroll
  for (int mi = 0; mi < 4; ++mi) {
    #pragma unroll
    for (int j = 0; j < 4; ++j) {
      const int row = wrow + mi*16 + quad*4 + j;
      const float r0v = rl[row*3], r1v = rl[row*3+1], r2v = rl[row*3+2];
      #pragma unroll
      for (int ni = 0; ni < 2; ++ni) {
        const int col = wcol + ni*16 + mcol;
        const int g = col >> 3, o = col & 7;
        const float v = acc[mi][ni][j] + bb[ni] + r0v*wr0[ni] + r1v*wr1[ni] + r2v*wr2[ni];
        S[row*64 + ((g ^ (row & 7)) << 3) + o] = f2h(v);
        s[ni] += v; s2[ni] += v*v;
      }
    }
  }
  #pragma unroll
  for (int ni = 0; ni < 2; ++ni) {
    s[ni]  += __shfl_xor(s[ni], 16);  s[ni]  += __shfl_xor(s[ni], 32);
    s2[ni] += __shfl_xor(s2[ni], 16); s2[ni] += __shfl_xor(s2[ni], 32);
  }
  if (quad == 0) {
    const int rh = w >> 1;
    #pragma unroll
    for (int ni = 0; ni < 2; ++ni) {
      const int col = wcol + ni*16 + mcol;
      ps[rh*128 + col]      = s[ni];
      ps[rh*128 + 64 + col] = s2[ni];
    }
  }
  __syncthreads();

  #pragma unroll
  for (int i = 0; i < 4; ++i) {
    const int u = i*256 + t;
    const int row = u >> 3, gg = u & 7;
    *(uint4*)(zah + (size_t)(r0 + row)*64 + gg*8) =
        *(const uint4*)(S + row*64 + ((gg ^ (row & 7)) << 3));
  }
  if (t < 128) atomicAdd(&midA[(blockIdx.x & 7)*128 + t], ps[t] + ps[128 + t]);
}

// ---------------- conv2 layer2: fp16 MFMA; BN from 8-copy midA ----------------
__global__ __launch_bounds__(256) void conv2_l2_mfma(
    const unsigned short* __restrict__ zah, const float* __restrict__ midA,
    const float* __restrict__ g1, const float* __restrict__ be1,
    const unsigned short* __restrict__ W2T, const float* __restrict__ b2,
    unsigned short* __restrict__ zhb, float* __restrict__ midB) {
  __shared__ unsigned short S[128*128];
  __shared__ float ps[512];
  __shared__ float scl[64], shl[64];
  const int r0 = blockIdx.x * 128;
  const int t = threadIdx.x;
  const int lane = t & 63, w = t >> 6;
  const int quad = lane >> 4, mcol = lane & 15;
  const float invR = 1.0f / (float)PK;

  if (t < 64) {
    float s = 0.0f, s2 = 0.0f;
    #pragma unroll
    for (int k = 0; k < 8; ++k) { s += midA[k*128 + t]; s2 += midA[k*128 + 64 + t]; }
    const float mu  = s * invR;
    const float var = s2 * invR - mu*mu;
    const float sc  = g1[t] * rsqrtf(var + 1e-5f);
    scl[t] = sc; shl[t] = be1[t] - mu*sc;
  }
  __syncthreads();

  {
    const int kb = t & 7, rr = t >> 3;
    float sc[8], sh[8];
    #pragma unroll
    for (int q = 0; q < 8; ++q) { sc[q] = scl[kb*8 + q]; sh[q] = shl[kb*8 + q]; }
    #pragma unroll
    for (int it = 0; it < 4; ++it) {
      const int r = rr + it*32;
      union { uint4 v; unsigned short s[8]; } in;
      in.v = *(const uint4*)(zah + (size_t)(r0 + r)*64 + kb*8);
      union { unsigned short s[8]; uint4 v; } o;
      #pragma unroll
      for (int q = 0; q < 8; ++q)
        o.s[q] = f2h(fmaxf(h2f(in.s[q])*sc[q] + sh[q], 0.0f));
      *(uint4*)(S + r*64 + ((kb ^ (r & 7)) * 8)) = o.v;
    }
  }
  __syncthreads();

  const int wrow = (w >> 1) * 64;
  const int wcol = (w & 1) * 64;

  f16x8 af[2][4], bfr[2][4];
  #pragma unroll
  for (int ks = 0; ks < 2; ++ks)
    #pragma unroll
    for (int mi = 0; mi < 4; ++mi) {
      const int row = wrow + mi*16 + mcol;
      af[ks][mi] = *(const f16x8*)(S + row*64 + (((ks*4 + quad) ^ (row & 7)) * 8));
    }
  #pragma unroll
  for (int ks = 0; ks < 2; ++ks)
    #pragma unroll
    for (int ni = 0; ni < 4; ++ni) {
      const int nr = wcol + ni*16 + mcol;
      bfr[ks][ni] = *(const f16x8*)(W2T + nr*64 + ks*32 + quad*8);
    }

  f32x4 acc[4][4];
  #pragma unroll
  for (int mi = 0; mi < 4; ++mi)
    #pragma unroll
    for (int ni = 0; ni < 4; ++ni)
      acc[mi][ni] = (f32x4){0.f, 0.f, 0.f, 0.f};

  #pragma unroll
  for (int ks = 0; ks < 2; ++ks)
    #pragma unroll
    for (int mi = 0; mi < 4; ++mi)
      #pragma unroll
      for (int ni = 0; ni < 4; ++ni)
        acc[mi][ni] = __builtin_amdgcn_mfma_f32_16x16x32_f16(af[ks][mi], bfr[ks][ni], acc[mi][ni], 0, 0, 0);

  __syncthreads();

  float bb[4];
  #pragma unroll
  for (int ni = 0; ni < 4; ++ni) bb[ni] = b2[wcol + ni*16 + mcol];
  float s[4] = {0,0,0,0}, s2[4] = {0,0,0,0};
  #pragma unroll
  for (int mi = 0; mi < 4; ++mi) {
    #pragma unroll
    for (int ni = 0; ni < 4; ++ni) {
      const int col = wcol + ni*16 + mcol;
      const int g = col >> 3, o = col & 7;
      #pragma unroll
      for (int j = 0; j < 4; ++j) {
        const int row = wrow + mi*16 + quad*4 + j;
        const float v = acc[mi][ni][j] + bb[ni];
        S[row*128 + ((g ^ (row & 15)) << 3) + o] = f2h(v);
        s[ni] += v; s2[ni] += v*v;
      }
    }
  }
  #pragma unroll
  for (int ni = 0; ni < 4; ++ni) {
    s[ni]  += __shfl_xor(s[ni], 16);  s[ni]  += __shfl_xor(s[ni], 32);
    s2[ni] += __shfl_xor(s2[ni], 16); s2[ni] += __shfl_xor(s2[ni], 32);
  }
  if (quad == 0) {
    const int rh = w >> 1;
    #pragma unroll
    for (int ni = 0; ni < 4; ++ni) {
      const int col = wcol + ni*16 + mcol;
      ps[rh*256 + col]       = s[ni];
      ps[rh*256 + 128 + col] = s2[ni];
    }
  }
  __syncthreads();

  #pragma unroll
  for (int i = 0; i < 8; ++i) {
    const int u = i*256 + t;
    const int row = u >> 4, gg = u & 15;
    *(uint4*)(zhb + (size_t)(r0 + row)*128 + gg*8) =
        *(const uint4*)(S + row*128 + ((gg ^ (row & 15)) << 3));
  }
  atomicAdd(&midB[(blockIdx.x & 7)*256 + t], ps[t] + ps[256 + t]);
}

// ---------------- R10: conv2 layer3 + max, 32x32x16, B served from LDS ----------------
// R9 post-mortem: lockstep sweep fixed FETCH (344->17.5 MB) but each block's 4 waves
// re-read the same 256 KB of B from global: 1 GB device-wide through L1/L2 (~29 µs
// at L2 ceiling) -> 66 µs, all pipes idle. R10: stage B through LDS once per block.
//  - 8 steps of 4 ct (32 KB = exactly As, dead after A-frag extraction).
//  - step s: wave w global-loads ct=s*4+w's 8 fragments (8 KB) to regs -> barrier ->
//    ds_write -> barrier -> all waves compute 4 chains (32 ds_read_b128 + 32 MFMA,
//    dep-distance 4). Global B volume drops 4x (268 MB ~ 8 µs L2); LDS serves the
//    4-way duplication at 69 TB/s (~8.5 µs/CU).
//  - per-wave col-maxes go straight to 4 w-indexed global planes (pm buffer gone).
// Arithmetic order identical to R9 -> bit-identical output (R9 absmax 0.0234).
__global__ __launch_bounds__(256, 4) void conv2_l3max_mfma32(
    const unsigned short* __restrict__ zhb, const float* __restrict__ midB,
    const float* __restrict__ g2, const float* __restrict__ be2,
    const unsigned short* __restrict__ W3T,
    float* __restrict__ pmax2) {
  __shared__ unsigned short As[128*128];   // 32 KB: zhb tile, then B staging
  __shared__ float scl[128], shl[128];     // 1 KB
  const int rb = blockIdx.x;
  const int r0 = rb * 128;
  const int t = threadIdx.x;
  const int lane = t & 63, w = t >> 6;
  const float invR = 1.0f / (float)PK;

  if (t < 128) {
    float s = 0.0f, s2 = 0.0f;
    #pragma unroll
    for (int k = 0; k < 8; ++k) { s += midB[k*256 + t]; s2 += midB[k*256 + 128 + t]; }
    const float mu  = s * invR;
    const float var = s2 * invR - mu*mu;
    const float sc  = g2[t] * rsqrtf(var + 1e-5f);
    scl[t] = sc; shl[t] = be2[t] - mu*sc;
  }
  __syncthreads();

  {
    const int kb = t & 15, rr = t >> 4;
    float sc[8], sh[8];
    #pragma unroll
    for (int q = 0; q < 8; ++q) { sc[q] = scl[kb*8 + q]; sh[q] = shl[kb*8 + q]; }
    #pragma unroll
    for (int it = 0; it < 8; ++it) {
      const int r = rr + it*16;
      union { uint4 v; unsigned short s[8]; } in;
      in.v = *(const uint4*)(zhb + (size_t)(r0 + r)*128 + kb*8);
      union { unsigned short s[8]; uint4 v; } o;
      #pragma unroll
      for (int q = 0; q < 8; ++q)
        o.s[q] = f2h(fmaxf(h2f(in.s[q])*sc[q] + sh[q], 0.0f));
      *(uint4*)(As + r*128 + ((kb ^ (r & 7)) * 8)) = o.v;
    }
  }
  __syncthreads();

  // ---- A fragments: wave w's 32 rows, all 8 k-groups -> 32 VGPRs, read ONCE ----
  const int row = w*32 + (lane & 31);
  const int khalf = lane >> 5;
  f16x8 af[8];
  #pragma unroll
  for (int ks = 0; ks < 8; ++ks) {
    const int g = ks*2 + khalf;
    af[ks] = *(const f16x8*)(As + row*128 + ((g ^ (row & 7)) * 8));
  }
  // (first loop barrier below covers "all af reads done before Bs overwrites As")

  unsigned short* const Bs = As;   // B staging buffer: 32 fragments x 1 KB

  #pragma unroll 1
  for (int s = 0; s < 8; ++s) {
    // wave w loads ct = s*4 + w's 8 fragments to regs (global, shared across blocks
    // in lockstep order -> L2-coherent, proven by R9's 17.5 MB FETCH)
    f16x8 tmp[8];
    #pragma unroll
    for (int j = 0; j < 8; ++j)
      tmp[j] = *(const f16x8*)(W3T + (((s*4 + w)*8 + j) << 9) + lane*8);
    __syncthreads();   // readers of previous step's Bs (or af extraction) done
    #pragma unroll
    for (int j = 0; j < 8; ++j)
      *(f16x8*)(Bs + (w*8 + j)*512 + lane*8) = tmp[j];
    __syncthreads();   // staged data visible to all waves

    f32x16 a0 = {}, a1 = {}, a2 = {}, a3 = {};
    #pragma unroll
    for (int ks = 0; ks < 8; ++ks) {
      const f16x8 b0 = *(const f16x8*)(Bs + (0*8 + ks)*512 + lane*8);
      const f16x8 b1 = *(const f16x8*)(Bs + (1*8 + ks)*512 + lane*8);
      const f16x8 b2 = *(const f16x8*)(Bs + (2*8 + ks)*512 + lane*8);
      const f16x8 b3 = *(const f16x8*)(Bs + (3*8 + ks)*512 + lane*8);
      a0 = __builtin_amdgcn_mfma_f32_32x32x16_f16(af[ks], b0, a0, 0, 0, 0);
      a1 = __builtin_amdgcn_mfma_f32_32x32x16_f16(af[ks], b1, a1, 0, 0, 0);
      a2 = __builtin_amdgcn_mfma_f32_32x32x16_f16(af[ks], b2, a2, 0, 0, 0);
      a3 = __builtin_amdgcn_mfma_f32_32x32x16_f16(af[ks], b3, a3, 0, 0, 0);
    }

    float m0 = -INFINITY, m1 = -INFINITY, m2 = -INFINITY, m3 = -INFINITY;
    #pragma unroll
    for (int r = 0; r < 16; ++r) {
      m0 = fmaxf(m0, a0[r]); m1 = fmaxf(m1, a1[r]);
      m2 = fmaxf(m2, a2[r]); m3 = fmaxf(m3, a3[r]);
    }
    m0 = fmaxf(m0, __shfl_xor(m0, 32));
    m1 = fmaxf(m1, __shfl_xor(m1, 32));
    m2 = fmaxf(m2, __shfl_xor(m2, 32));
    m3 = fmaxf(m3, __shfl_xor(m3, 32));
    if (lane < 32) {
      const size_t base = ((size_t)w << 20) + (size_t)rb*1024 + (size_t)(s*4)*32 + lane;
      pmax2[base]      = m0;
      pmax2[base + 32] = m1;
      pmax2[base + 64] = m2;
      pmax2[base + 96] = m3;
    }
  }
}

// ---------------- fused per-graph max pool (4 planes) + final linear partials ----------------
__global__ __launch_bounds__(256) void poollin_kernel(const float* __restrict__ pmax2,
    const float* __restrict__ b3, const float* __restrict__ W,
    float* __restrict__ zpart) {
  __shared__ float gs[256];
  const int b = blockIdx.x >> 2, q = blockIdx.x & 3;
  const int t = threadIdx.x;
  const int c = q*256 + t;
  const float* p = pmax2 + (size_t)b*128*1024 + c;
  float m = -INFINITY;
  #pragma unroll 4
  for (int rb = 0; rb < 128; ++rb) {
    const size_t o = (size_t)rb*1024;
    m = fmaxf(m, fmaxf(fmaxf(p[o], p[o + (1u << 20)]),
                       fmaxf(p[o + (2u << 20)], p[o + (3u << 20)])));
  }
  gs[t] = m + b3[c];
  __syncthreads();
  const float* Wq = W + (size_t)q*256*256;
  float acc = 0.0f;
  for (int cc = 0; cc < 256; ++cc) acc += gs[cc] * Wq[cc*256 + t];
  zpart[blockIdx.x*256 + t] = acc;
}

// ---------------- final BN(8 rows) + relu ----------------
__global__ __launch_bounds__(256) void final_kernel(const float* __restrict__ zpart,
    const float* __restrict__ lb, const float* __restrict__ lg,
    const float* __restrict__ lbe, float* __restrict__ out) {
  const int o = threadIdx.x;
  float z[NB]; float s = 0.0f, s2 = 0.0f;
  #pragma unroll
  for (int b = 0; b < NB; ++b) {
    float v = lb[o];
    #pragma unroll
    for (int q = 0; q < 4; ++q) v += zpart[(b*4+q)*256 + o];
    z[b] = v; s += v; s2 += v*v;
  }
  const float mu  = s * 0.125f;
  const float var = s2 * 0.125f - mu*mu;
  const float inv = rsqrtf(var + 1e-5f);
  const float sc = lg[o]*inv, sh = lbe[o] - mu*sc;
  #pragma unroll
  for (int b = 0; b < NB; ++b) out[b*256 + o] = fmaxf(z[b]*sc + sh, 0.0f);
}

extern "C" void kernel_launch(void* const* d_in, const int* in_sizes, int n_in,
                              void* d_out, int out_size, void* d_ws, size_t ws_size,
                              hipStream_t stream) {
  const float* pos    = (const float*)d_in[0];
  const float* c1_W1  = (const float*)d_in[2];
  const float* c1_b1  = (const float*)d_in[3];
  const float* c1_g1  = (const float*)d_in[4];
  const float* c1_be1 = (const float*)d_in[5];
  const float* c1_W2  = (const float*)d_in[6];
  const float* c1_b2  = (const float*)d_in[7];
  const float* c2_W1  = (const float*)d_in[8];
  const float* c2_b1  = (const float*)d_in[9];
  const float* c2_g1  = (const float*)d_in[10];
  const float* c2_be1 = (const float*)d_in[11];
  const float* c2_W2  = (const float*)d_in[12];
  const float* c2_b2  = (const float*)d_in[13];
  const float* c2_g2  = (const float*)d_in[14];
  const float* c2_be2 = (const float*)d_in[15];
  const float* c2_W3  = (const float*)d_in[16];
  const float* c2_b3  = (const float*)d_in[17];
  const float* lin_W  = (const float*)d_in[18];
  const float* lin_b  = (const float*)d_in[19];
  const float* lin_g  = (const float*)d_in[20];
  const float* lin_be = (const float*)d_in[21];
  float* out = (float*)d_out;

  char* ws = (char*)d_ws;
  int*   idx     = (int*)  (ws + 0);                 // 512 KB
  float* rel     = (float*)(ws + 524288);            // 1.5 MB
  float* zpart   = (float*)(ws + 2097152 + 2048);    // 8 KB
  float* mid1    = (float*)(ws + 2164736);           // } zeroed by
  float* midA    = (float*)(ws + 2164736 + 4096);    // } wprep
  float* midB    = (float*)(ws + 2164736 + 8192);    // } block 140
  unsigned short* W2T   = (unsigned short*)(ws + 2295808);
  unsigned short* w1T   = (unsigned short*)(ws + 2312192);
  unsigned short* W2c1T = (unsigned short*)(ws + 2320384);
  unsigned short* z1h = (unsigned short*)(ws + 2426880);    // 16 MB
  unsigned short* zah = (unsigned short*)(ws + 2426880);    // reuses z1h region (dead)
  float* pmax2   = (float*)(ws + 2426880);                  // 4 planes x 4 MB = 16 MB
  unsigned short* x1h = (unsigned short*)(ws + 35981312);   // 1 MB fp16
  unsigned short* zhb = (unsigned short*)(ws + 38078464);   // 33.5 MB
  unsigned short* W3T = (unsigned short*)(ws + 71632896);   // 256 KB

  wprep_kernel<<<141, 256, 0, stream>>>(c2_W3, c2_W2, c2_W1, c1_W2, W3T, W2T, w1T, W2c1T, mid1);
  knn_conv1_kernel<<<PTS/4, 256, 0, stream>>>(pos, c1_W1, c1_b1, idx, rel, z1h, mid1);
  conv1_l2max_mfma<<<PK/128, 256, 0, stream>>>(z1h, mid1, c1_g1, c1_be1, W2c1T, c1_b2, x1h);
  conv2_l1_mfma<<<PK/128, 256, 0, stream>>>(x1h, idx, rel, w1T, c2_W1, c2_b1, zah, midA);
  conv2_l2_mfma<<<PK/128, 256, 0, stream>>>(zah, midA, c2_g1, c2_be1, W2T, c2_b2, zhb, midB);
  conv2_l3max_mfma32<<<PK/128, 256, 0, stream>>>(zhb, midB, c2_g2, c2_be2, W3T, pmax2);
  poollin_kernel<<<NB*4, 256, 0, stream>>>(pmax2, c2_b3, lin_W, zpart);
  final_kernel<<<1, 256, 0, stream>>>(zpart, lin_b, lin_g, lin_be, out);
}

// Round 11
// 222.006 us; speedup vs baseline: 1.4080x; 1.0775x over previous
//
#include <hip/hip_runtime.h>
#include <math.h>

#define NB   8
#define NPTS 1024
#define PTS  8192      // NB*NPTS
#define KNN  16
#define PK   (PTS*KNN) // 131072

typedef __attribute__((ext_vector_type(8))) _Float16 f16x8;
typedef __attribute__((ext_vector_type(4))) float f32x4;

__device__ __forceinline__ unsigned short f2h(float f) {
  _Float16 h = (_Float16)f;
  union { _Float16 h; unsigned short u; } c; c.h = h;
  return c.u;
}
__device__ __forceinline__ float h2f(unsigned short u) {
  union { unsigned short u; _Float16 h; } c; c.u = u;
  return (float)c.h;
}
__device__ __forceinline__ int lanerank(unsigned long long m) {
  return __builtin_amdgcn_mbcnt_hi((unsigned)(m >> 32),
         __builtin_amdgcn_mbcnt_lo((unsigned)m, 0));
}

// ---------------- kNN + conv1 layer1 fused: one WAVE per point ----------------
// R3 WIN: bitonic sort replaced by exact radix-SELECT; 54.7 -> <45 µs.
__global__ __launch_bounds__(256) void knn_conv1_kernel(const float* __restrict__ pos,
    const float* __restrict__ W1, const float* __restrict__ b1,
    int* __restrict__ idx, float* __restrict__ rel,
    unsigned short* __restrict__ z1h, float* __restrict__ mid1) {
  __shared__ float px[NPTS], py[NPTS], pz[NPTS];
  __shared__ float feat[4][KNN][6];
  __shared__ float ls[256], ls2[256];
  const int t = threadIdx.x;
  const int wv = t >> 6, lane = t & 63;
  const int b = blockIdx.x;
  const int graph = b >> 8;
  const int base = graph << 10;
  for (int j = t; j < NPTS; j += 256) {
    px[j] = pos[3*(base+j)];
    py[j] = pos[3*(base+j)+1];
    pz[j] = pos[3*(base+j)+2];
  }
  __syncthreads();

  const int il = ((b & 255) << 2) + wv;
  const int i  = base + il;
  const float pix = px[il], piy = py[il], piz = pz[il];
  const float sqi = pix*pix + piy*piy + piz*piz;

  unsigned key[16];
  #pragma unroll
  for (int q = 0; q < 16; ++q) {
    const int j = (q << 6) + lane;
    const float x = px[j], y = py[j], z = pz[j];
    const float sqj = x*x + y*y + z*z;
    const float dt  = pix*x + piy*y + piz*z;
    const float d   = sqi + sqj - 2.0f*dt;
    const unsigned db = __float_as_uint(d);
    key[q] = (db >> 31) ? ~db : (db | 0x80000000u);
  }

  unsigned V = 0;
  #pragma unroll 1
  for (int bb = 31; bb >= 0; --bb) {
    const unsigned test = V | (1u << bb);
    int cnt = 0;
    #pragma unroll
    for (int q = 0; q < 16; ++q)
      cnt += __popcll(__ballot(key[q] < test));
    if (cnt < 16) V = test;
  }

  int c = 0;
  #pragma unroll
  for (int q = 0; q < 16; ++q)
    c += __popcll(__ballot(key[q] < V));

  int p_lt = 0, p_eq = c;
  #pragma unroll 1
  for (int q = 0; q < 16; ++q) {
    const unsigned long long mlt = __ballot(key[q] < V);
    const unsigned long long meq = __ballot(key[q] == V);
    int slot = -1;
    if (key[q] < V) slot = p_lt + lanerank(mlt);
    else if (key[q] == V) {
      const int s = p_eq + lanerank(meq);
      if (s < 16) slot = s;
    }
    if (slot >= 0) {
      const int j = (q << 6) + lane;
      const int r = i*KNN + slot;
      const float rx = px[j] - pix, ry = py[j] - piy, rz = pz[j] - piz;
      idx[r] = base + j;
      rel[3*r] = rx; rel[3*r+1] = ry; rel[3*r+2] = rz;
      feat[wv][slot][0] = px[j]; feat[wv][slot][1] = py[j]; feat[wv][slot][2] = pz[j];
      feat[wv][slot][3] = rx;    feat[wv][slot][4] = ry;    feat[wv][slot][5] = rz;
    }
    p_lt += __popcll(mlt);
    p_eq += __popcll(meq);
  }

  float w[6];
  #pragma unroll
  for (int q = 0; q < 6; ++q) w[q] = W1[q*64 + lane];
  const float bbv = b1[lane];
  float s = 0.0f, s2 = 0.0f;
  #pragma unroll
  for (int k = 0; k < KNN; ++k) {
    float z = bbv;
    #pragma unroll
    for (int q = 0; q < 6; ++q) z += feat[wv][k][q]*w[q];
    z1h[(size_t)(i*KNN + k)*64 + lane] = f2h(z);
    s += z; s2 += z*z;
  }
  ls[t] = s; ls2[t] = s2;
  __syncthreads();
  if (t < 64) {
    float a  = ls[t] + ls[t+64] + ls[t+128] + ls[t+192];
    float a2 = ls2[t] + ls2[t+64] + ls2[t+128] + ls2[t+192];
    const int cp = (b & 7) * 128;
    atomicAdd(&mid1[cp + t], a);
    atomicAdd(&mid1[cp + 64 + t], a2);
  }
}

// ---------------- weight prep (block 140 zeroes mid1/midA/midB) ----------------
// R11: ALL B operands in MFMA-fragment order (R2 technique, R1's split-gather fix):
//  W3T  (16x16 frags, nb*4+ks): W3T[((nb*4+ks)<<9) + lane*8+e] = W3[k=ks*32+(lane>>4)*8+e][n=nb*16+(lane&15)]
//  W2T/w1T/W2c1T (16-col x 32-k frags, nt*2+ks): [((nt*2+ks)<<9) + lane*8+e] =
//      Wsrc[k=ks*32+(lane>>4)*8+e][n=nt*16+(lane&15)]  — bit-identical values, coalesced loads.
__global__ __launch_bounds__(256) void wprep_kernel(const float* __restrict__ W3,
    const float* __restrict__ W2, const float* __restrict__ W1c2,
    const float* __restrict__ W2c1,
    unsigned short* __restrict__ W3T, unsigned short* __restrict__ W2T,
    unsigned short* __restrict__ w1T, unsigned short* __restrict__ W2c1T,
    float* __restrict__ mids) {
  const int b = blockIdx.x, t = threadIdx.x;
  if (b < 128) {
    const int k = b;
    const int ks = k >> 5, qd = (k >> 3) & 3, e = k & 7;
    for (int n = t; n < 1024; n += 256) {
      const int nb = n >> 4, mc = n & 15;
      W3T[((nb*4 + ks) << 9) + qd*128 + mc*8 + e] = f2h(W3[(size_t)k*1024 + n]);
    }
  } else if (b < 132) {
    for (int id = (b-128)*2048 + t; id < (b-127)*2048; id += 256) {
      const int n = id >> 6, k = id & 63;
      const int nt = n >> 4, mc = n & 15, ks = k >> 5, qd = (k >> 3) & 3, e = k & 7;
      W2T[((nt*2 + ks) << 9) + qd*128 + mc*8 + e] = f2h(W2[k*128 + n]);
    }
  } else if (b < 136) {
    for (int id = (b-132)*1024 + t; id < (b-131)*1024; id += 256) {
      const int n = id >> 6, k = id & 63;
      const int nt = n >> 4, mc = n & 15, ks = k >> 5, qd = (k >> 3) & 3, e = k & 7;
      w1T[((nt*2 + ks) << 9) + qd*128 + mc*8 + e] = f2h(W1c2[k*64 + n]);
    }
  } else if (b < 140) {
    for (int id = (b-136)*1024 + t; id < (b-135)*1024; id += 256) {
      const int n = id >> 6, k = id & 63;
      const int nt = n >> 4, mc = n & 15, ks = k >> 5, qd = (k >> 3) & 3, e = k & 7;
      W2c1T[((nt*2 + ks) << 9) + qd*128 + mc*8 + e] = f2h(W2c1[k*64 + n]);
    }
  } else {
    for (int i2 = t; i2 < 4096; i2 += 256) mids[i2] = 0.0f;
  }
}

// ---------------- conv1 layer2 + max: fp16 MFMA; BN finalized from 8-copy mid1 ----------------
__global__ __launch_bounds__(256) void conv1_l2max_mfma(
    const unsigned short* __restrict__ z1h, const float* __restrict__ mid1,
    const float* __restrict__ g1, const float* __restrict__ be1,
    const unsigned short* __restrict__ W2T, const float* __restrict__ b2,
    unsigned short* __restrict__ x1h) {
  __shared__ unsigned short As[128*64];
  __shared__ float scl[64], shl[64];
  const int r0 = blockIdx.x * 128;
  const int t = threadIdx.x;
  const int lane = t & 63, w = t >> 6;
  const int quad = lane >> 4, mcol = lane & 15;
  const float invR = 1.0f / (float)PK;

  if (t < 64) {
    float s = 0.0f, s2 = 0.0f;
    #pragma unroll
    for (int k = 0; k < 8; ++k) { s += mid1[k*128 + t]; s2 += mid1[k*128 + 64 + t]; }
    const float mu  = s * invR;
    const float var = s2 * invR - mu*mu;
    const float sc  = g1[t] * rsqrtf(var + 1e-5f);
    scl[t] = sc; shl[t] = be1[t] - mu*sc;
  }
  __syncthreads();

  {
    const int kb = t & 7, rr = t >> 3;
    float sc[8], sh[8];
    #pragma unroll
    for (int q = 0; q < 8; ++q) { sc[q] = scl[kb*8 + q]; sh[q] = shl[kb*8 + q]; }
    #pragma unroll
    for (int it = 0; it < 4; ++it) {
      const int r = rr + it*32;
      union { uint4 v; unsigned short s[8]; } in;
      in.v = *(const uint4*)(z1h + (size_t)(r0 + r)*64 + kb*8);
      union { unsigned short s[8]; uint4 v; } o;
      #pragma unroll
      for (int q = 0; q < 8; ++q)
        o.s[q] = f2h(fmaxf(h2f(in.s[q])*sc[q] + sh[q], 0.0f));
      *(uint4*)(As + r*64 + ((kb ^ (r & 7)) * 8)) = o.v;
    }
  }
  __syncthreads();

  const int wrow = (w >> 1) * 64;
  const int wncol = (w & 1) * 32;

  f32x4 acc[4][2];
  #pragma unroll
  for (int mi = 0; mi < 4; ++mi)
    #pragma unroll
    for (int ni = 0; ni < 2; ++ni)
      acc[mi][ni] = (f32x4){0.f, 0.f, 0.f, 0.f};

  #pragma unroll
  for (int ks = 0; ks < 2; ++ks) {
    f16x8 af[4], bfr[2];
    #pragma unroll
    for (int mi = 0; mi < 4; ++mi) {
      const int row = wrow + mi*16 + mcol;
      af[mi] = *(const f16x8*)(As + row*64 + (((ks*4 + quad) ^ (row & 7)) * 8));
    }
    #pragma unroll
    for (int ni = 0; ni < 2; ++ni)
      bfr[ni] = *(const f16x8*)(W2T + ((((w & 1)*2 + ni)*2 + ks) << 9) + lane*8);
    #pragma unroll
    for (int mi = 0; mi < 4; ++mi)
      #pragma unroll
      for (int ni = 0; ni < 2; ++ni)
        acc[mi][ni] = __builtin_amdgcn_mfma_f32_16x16x32_f16(af[mi], bfr[ni], acc[mi][ni], 0, 0, 0);
  }

  float bb[2];
  #pragma unroll
  for (int ni = 0; ni < 2; ++ni) bb[ni] = b2[wncol + ni*16 + mcol];
  #pragma unroll
  for (int mi = 0; mi < 4; ++mi) {
    const int p = blockIdx.x*8 + (w >> 1)*4 + mi;
    #pragma unroll
    for (int ni = 0; ni < 2; ++ni) {
      f32x4 a = acc[mi][ni];
      float m = fmaxf(fmaxf(a[0], a[1]), fmaxf(a[2], a[3]));
      m = fmaxf(m, __shfl_xor(m, 16));
      m = fmaxf(m, __shfl_xor(m, 32));
      if (quad == 0) x1h[(size_t)p*64 + wncol + ni*16 + mcol] = f2h(m + bb[ni]);
    }
  }
}

// ---------------- conv2 layer1: fp16 MFMA (gather + rank-3 rel fixup) ----------------
__global__ __launch_bounds__(256) void conv2_l1_mfma(
    const unsigned short* __restrict__ x1h, const int* __restrict__ idx,
    const float* __restrict__ rel, const unsigned short* __restrict__ w1T,
    const float* __restrict__ W1full, const float* __restrict__ b1,
    unsigned short* __restrict__ zah, float* __restrict__ midA) {
  __shared__ unsigned short S[128*64];
  __shared__ int   idxr[128];
  __shared__ float rl[128*3];
  __shared__ float ps[256];
  const int r0 = blockIdx.x * 128;
  const int t = threadIdx.x;
  const int lane = t & 63, w = t >> 6;
  const int quad = lane >> 4, mcol = lane & 15;

  if (t < 128) idxr[t] = idx[r0 + t];
  else if (t < 224) *(float4*)(rl + (t-128)*4) = *(const float4*)(rel + (size_t)r0*3 + (t-128)*4);
  __syncthreads();

  {
    const int kb = t & 7, rr = t >> 3;
    #pragma unroll
    for (int it = 0; it < 4; ++it) {
      const int r = rr + it*32;
      const int gj = idxr[r];
      const uint4 v = *(const uint4*)(x1h + (size_t)gj*64 + kb*8);
      *(uint4*)(S + r*64 + ((kb ^ (r & 7)) * 8)) = v;
    }
  }
  __syncthreads();

  const int wrow = (w >> 1) * 64;
  const int wcol = (w & 1) * 32;

  f16x8 af[2][4], bfr[2][2];
  #pragma unroll
  for (int ks = 0; ks < 2; ++ks)
    #pragma unroll
    for (int mi = 0; mi < 4; ++mi) {
      const int row = wrow + mi*16 + mcol;
      af[ks][mi] = *(const f16x8*)(S + row*64 + (((ks*4 + quad) ^ (row & 7)) * 8));
    }
  #pragma unroll
  for (int ks = 0; ks < 2; ++ks)
    #pragma unroll
    for (int ni = 0; ni < 2; ++ni)
      bfr[ks][ni] = *(const f16x8*)(w1T + ((((w & 1)*2 + ni)*2 + ks) << 9) + lane*8);

  f32x4 acc[4][2];
  #pragma unroll
  for (int mi = 0; mi < 4; ++mi)
    #pragma unroll
    for (int ni = 0; ni < 2; ++ni)
      acc[mi][ni] = (f32x4){0.f, 0.f, 0.f, 0.f};

  #pragma unroll
  for (int ks = 0; ks < 2; ++ks)
    #pragma unroll
    for (int mi = 0; mi < 4; ++mi)
      #pragma unroll
      for (int ni = 0; ni < 2; ++ni)
        acc[mi][ni] = __builtin_amdgcn_mfma_f32_16x16x32_f16(af[ks][mi], bfr[ks][ni], acc[mi][ni], 0, 0, 0);

  __syncthreads();

  float bb[2], wr0[2], wr1[2], wr2[2];
  #pragma unroll
  for (int ni = 0; ni < 2; ++ni) {
    const int col = wcol + ni*16 + mcol;
    bb[ni]  = b1[col];
    wr0[ni] = W1full[64*64 + col];
    wr1[ni] = W1full[65*64 + col];
    wr2[ni] = W1full[66*64 + col];
  }
  float s[2] = {0,0}, s2[2] = {0,0};
  #pragma unroll
  for (int mi = 0; mi < 4; ++mi) {
    #pragma unroll
    for (int j = 0; j < 4; ++j) {
      const int row = wrow + mi*16 + quad*4 + j;
      const float r0v = rl[row*3], r1v = rl[row*3+1], r2v = rl[row*3+2];
      #pragma unroll
      for (int ni = 0; ni < 2; ++ni) {
        const int col = wcol + ni*16 + mcol;
        const int g = col >> 3, o = col & 7;
        const float v = acc[mi][ni][j] + bb[ni] + r0v*wr0[ni] + r1v*wr1[ni] + r2v*wr2[ni];
        S[row*64 + ((g ^ (row & 7)) << 3) + o] = f2h(v);
        s[ni] += v; s2[ni] += v*v;
      }
    }
  }
  #pragma unroll
  for (int ni = 0; ni < 2; ++ni) {
    s[ni]  += __shfl_xor(s[ni], 16);  s[ni]  += __shfl_xor(s[ni], 32);
    s2[ni] += __shfl_xor(s2[ni], 16); s2[ni] += __shfl_xor(s2[ni], 32);
  }
  if (quad == 0) {
    const int rh = w >> 1;
    #pragma unroll
    for (int ni = 0; ni < 2; ++ni) {
      const int col = wcol + ni*16 + mcol;
      ps[rh*128 + col]      = s[ni];
      ps[rh*128 + 64 + col] = s2[ni];
    }
  }
  __syncthreads();

  #pragma unroll
  for (int i = 0; i < 4; ++i) {
    const int u = i*256 + t;
    const int row = u >> 3, gg = u & 7;
    *(uint4*)(zah + (size_t)(r0 + row)*64 + gg*8) =
        *(const uint4*)(S + row*64 + ((gg ^ (row & 7)) << 3));
  }
  if (t < 128) atomicAdd(&midA[(blockIdx.x & 7)*128 + t], ps[t] + ps[128 + t]);
}

// ---------------- conv2 layer2: fp16 MFMA; BN from 8-copy midA ----------------
__global__ __launch_bounds__(256) void conv2_l2_mfma(
    const unsigned short* __restrict__ zah, const float* __restrict__ midA,
    const float* __restrict__ g1, const float* __restrict__ be1,
    const unsigned short* __restrict__ W2T, const float* __restrict__ b2,
    unsigned short* __restrict__ zhb, float* __restrict__ midB) {
  __shared__ unsigned short S[128*128];
  __shared__ float ps[512];
  __shared__ float scl[64], shl[64];
  const int r0 = blockIdx.x * 128;
  const int t = threadIdx.x;
  const int lane = t & 63, w = t >> 6;
  const int quad = lane >> 4, mcol = lane & 15;
  const float invR = 1.0f / (float)PK;

  if (t < 64) {
    float s = 0.0f, s2 = 0.0f;
    #pragma unroll
    for (int k = 0; k < 8; ++k) { s += midA[k*128 + t]; s2 += midA[k*128 + 64 + t]; }
    const float mu  = s * invR;
    const float var = s2 * invR - mu*mu;
    const float sc  = g1[t] * rsqrtf(var + 1e-5f);
    scl[t] = sc; shl[t] = be1[t] - mu*sc;
  }
  __syncthreads();

  {
    const int kb = t & 7, rr = t >> 3;
    float sc[8], sh[8];
    #pragma unroll
    for (int q = 0; q < 8; ++q) { sc[q] = scl[kb*8 + q]; sh[q] = shl[kb*8 + q]; }
    #pragma unroll
    for (int it = 0; it < 4; ++it) {
      const int r = rr + it*32;
      union { uint4 v; unsigned short s[8]; } in;
      in.v = *(const uint4*)(zah + (size_t)(r0 + r)*64 + kb*8);
      union { unsigned short s[8]; uint4 v; } o;
      #pragma unroll
      for (int q = 0; q < 8; ++q)
        o.s[q] = f2h(fmaxf(h2f(in.s[q])*sc[q] + sh[q], 0.0f));
      *(uint4*)(S + r*64 + ((kb ^ (r & 7)) * 8)) = o.v;
    }
  }
  __syncthreads();

  const int wrow = (w >> 1) * 64;
  const int wcol = (w & 1) * 64;

  f16x8 af[2][4], bfr[2][4];
  #pragma unroll
  for (int ks = 0; ks < 2; ++ks)
    #pragma unroll
    for (int mi = 0; mi < 4; ++mi) {
      const int row = wrow + mi*16 + mcol;
      af[ks][mi] = *(const f16x8*)(S + row*64 + (((ks*4 + quad) ^ (row & 7)) * 8));
    }
  #pragma unroll
  for (int ks = 0; ks < 2; ++ks)
    #pragma unroll
    for (int ni = 0; ni < 4; ++ni)
      bfr[ks][ni] = *(const f16x8*)(W2T + ((((w & 1)*4 + ni)*2 + ks) << 9) + lane*8);

  f32x4 acc[4][4];
  #pragma unroll
  for (int mi = 0; mi < 4; ++mi)
    #pragma unroll
    for (int ni = 0; ni < 4; ++ni)
      acc[mi][ni] = (f32x4){0.f, 0.f, 0.f, 0.f};

  #pragma unroll
  for (int ks = 0; ks < 2; ++ks)
    #pragma unroll
    for (int mi = 0; mi < 4; ++mi)
      #pragma unroll
      for (int ni = 0; ni < 4; ++ni)
        acc[mi][ni] = __builtin_amdgcn_mfma_f32_16x16x32_f16(af[ks][mi], bfr[ks][ni], acc[mi][ni], 0, 0, 0);

  __syncthreads();

  float bb[4];
  #pragma unroll
  for (int ni = 0; ni < 4; ++ni) bb[ni] = b2[wcol + ni*16 + mcol];
  float s[4] = {0,0,0,0}, s2[4] = {0,0,0,0};
  #pragma unroll
  for (int mi = 0; mi < 4; ++mi) {
    #pragma unroll
    for (int ni = 0; ni < 4; ++ni) {
      const int col = wcol + ni*16 + mcol;
      const int g = col >> 3, o = col & 7;
      #pragma unroll
      for (int j = 0; j < 4; ++j) {
        const int row = wrow + mi*16 + quad*4 + j;
        const float v = acc[mi][ni][j] + bb[ni];
        S[row*128 + ((g ^ (row & 15)) << 3) + o] = f2h(v);
        s[ni] += v; s2[ni] += v*v;
      }
    }
  }
  #pragma unroll
  for (int ni = 0; ni < 4; ++ni) {
    s[ni]  += __shfl_xor(s[ni], 16);  s[ni]  += __shfl_xor(s[ni], 32);
    s2[ni] += __shfl_xor(s2[ni], 16); s2[ni] += __shfl_xor(s2[ni], 32);
  }
  if (quad == 0) {
    const int rh = w >> 1;
    #pragma unroll
    for (int ni = 0; ni < 4; ++ni) {
      const int col = wcol + ni*16 + mcol;
      ps[rh*256 + col]       = s[ni];
      ps[rh*256 + 128 + col] = s2[ni];
    }
  }
  __syncthreads();

  #pragma unroll
  for (int i = 0; i < 8; ++i) {
    const int u = i*256 + t;
    const int row = u >> 4, gg = u & 15;
    *(uint4*)(zhb + (size_t)(r0 + row)*128 + gg*8) =
        *(const uint4*)(S + row*128 + ((gg ^ (row & 15)) << 3));
  }
  atomicAdd(&midB[(blockIdx.x & 7)*256 + t], ps[t] + ps[256 + t]);
}

// ---------------- conv2 layer3 + full max fusion (R4-proven 16x16 version) ----------------
// R8-R10 32x32 excursion reverted (net-negative vs this kernel). Lessons kept:
// phase-coherent lockstep B sweeps get L2-cached (R9: FETCH 344->17.5 MB);
// intra-block operand duplication belongs in LDS (R10).
// This kernel: ONE block per 128-row tile, 16 chunks of 64 cols, W3T in R2
// fragment order (coalesced B), scl/shl overlaid into pm, LDS 40960 -> 4 blocks/CU.
__global__ __launch_bounds__(256, 3) void conv2_l3max_mfma(
    const unsigned short* __restrict__ zhb, const float* __restrict__ midB,
    const float* __restrict__ g2, const float* __restrict__ be2,
    const unsigned short* __restrict__ W3T,
    float* __restrict__ pmax2) {
  __shared__ unsigned short As[128*128];
  __shared__ float pm[2048];   // [rowhalf][1024]; first 256 floats double as scl/shl during staging
  float* const scl = pm;
  float* const shl = pm + 128;
  const int rb = blockIdx.x;
  const int r0 = rb * 128;
  const int t = threadIdx.x;
  const int lane = t & 63, w = t >> 6;
  const int quad = lane >> 4, mcol = lane & 15;
  const float invR = 1.0f / (float)PK;

  if (t < 128) {
    float s = 0.0f, s2 = 0.0f;
    #pragma unroll
    for (int k = 0; k < 8; ++k) { s += midB[k*256 + t]; s2 += midB[k*256 + 128 + t]; }
    const float mu  = s * invR;
    const float var = s2 * invR - mu*mu;
    const float sc  = g2[t] * rsqrtf(var + 1e-5f);
    scl[t] = sc; shl[t] = be2[t] - mu*sc;
  }
  __syncthreads();

  {
    const int kb = t & 15, rr = t >> 4;
    float sc[8], sh[8];
    #pragma unroll
    for (int q = 0; q < 8; ++q) { sc[q] = scl[kb*8 + q]; sh[q] = shl[kb*8 + q]; }
    #pragma unroll
    for (int it = 0; it < 8; ++it) {
      const int r = rr + it*16;
      union { uint4 v; unsigned short s[8]; } in;
      in.v = *(const uint4*)(zhb + (size_t)(r0 + r)*128 + kb*8);
      union { unsigned short s[8]; uint4 v; } o;
      #pragma unroll
      for (int q = 0; q < 8; ++q)
        o.s[q] = f2h(fmaxf(h2f(in.s[q])*sc[q] + sh[q], 0.0f));
      *(uint4*)(As + r*128 + ((kb ^ (r & 7)) * 8)) = o.v;
    }
  }
  __syncthreads();   // after this, scl/shl dead -> pm writable

  const int wrow = (w >> 1) * 64;
  const int wncol = (w & 1) * 32;
  const int rh = w >> 1;

  #pragma unroll 1
  for (int chunk = 0; chunk < 16; ++chunk) {
    const int nb0 = chunk*4 + (w & 1)*2;

    f32x4 acc[4][2];
    #pragma unroll
    for (int mi = 0; mi < 4; ++mi)
      #pragma unroll
      for (int ni = 0; ni < 2; ++ni)
        acc[mi][ni] = (f32x4){0.f, 0.f, 0.f, 0.f};

    #pragma unroll
    for (int ks = 0; ks < 4; ++ks) {
      f16x8 bfr[2], af[4];
      #pragma unroll
      for (int ni = 0; ni < 2; ++ni)
        bfr[ni] = *(const f16x8*)(W3T + (((nb0 + ni)*4 + ks) << 9) + lane*8);
      #pragma unroll
      for (int mi = 0; mi < 4; ++mi) {
        const int row = wrow + mi*16 + mcol;
        af[mi] = *(const f16x8*)(As + row*128 + (((ks*4 + quad) ^ (row & 7)) * 8));
      }
      #pragma unroll
      for (int mi = 0; mi < 4; ++mi)
        #pragma unroll
        for (int ni = 0; ni < 2; ++ni)
          acc[mi][ni] = __builtin_amdgcn_mfma_f32_16x16x32_f16(af[mi], bfr[ni], acc[mi][ni], 0, 0, 0);
    }

    #pragma unroll
    for (int ni = 0; ni < 2; ++ni) {
      float m4 = -INFINITY;
      #pragma unroll
      for (int mi = 0; mi < 4; ++mi) {
        f32x4 a = acc[mi][ni];
        m4 = fmaxf(m4, fmaxf(fmaxf(a[0], a[1]), fmaxf(a[2], a[3])));
      }
      m4 = fmaxf(m4, __shfl_xor(m4, 16));
      m4 = fmaxf(m4, __shfl_xor(m4, 32));
      if (quad == 0)
        pm[rh*1024 + chunk*64 + wncol + ni*16 + mcol] = m4;
    }
  }
  __syncthreads();

  #pragma unroll
  for (int i = 0; i < 4; ++i) {
    const int c = i*256 + t;
    pmax2[(size_t)rb*1024 + c] = fmaxf(pm[c], pm[1024 + c]);
  }
}

// ---------------- fused per-graph max pool + final linear partials ----------------
__global__ __launch_bounds__(256) void poollin_kernel(const float* __restrict__ pmax2,
    const float* __restrict__ b3, const float* __restrict__ W,
    float* __restrict__ zpart) {
  __shared__ float gs[256];
  const int b = blockIdx.x >> 2, q = blockIdx.x & 3;
  const int t = threadIdx.x;
  const int c = q*256 + t;
  const float* p = pmax2 + (size_t)b*128*1024 + c;
  float m = -INFINITY;
  #pragma unroll 4
  for (int rb = 0; rb < 128; ++rb) m = fmaxf(m, p[(size_t)rb*1024]);
  gs[t] = m + b3[c];
  __syncthreads();
  const float* Wq = W + (size_t)q*256*256;
  float acc = 0.0f;
  for (int cc = 0; cc < 256; ++cc) acc += gs[cc] * Wq[cc*256 + t];
  zpart[blockIdx.x*256 + t] = acc;
}

// ---------------- final BN(8 rows) + relu ----------------
__global__ __launch_bounds__(256) void final_kernel(const float* __restrict__ zpart,
    const float* __restrict__ lb, const float* __restrict__ lg,
    const float* __restrict__ lbe, float* __restrict__ out) {
  const int o = threadIdx.x;
  float z[NB]; float s = 0.0f, s2 = 0.0f;
  #pragma unroll
  for (int b = 0; b < NB; ++b) {
    float v = lb[o];
    #pragma unroll
    for (int q = 0; q < 4; ++q) v += zpart[(b*4+q)*256 + o];
    z[b] = v; s += v; s2 += v*v;
  }
  const float mu  = s * 0.125f;
  const float var = s2 * 0.125f - mu*mu;
  const float inv = rsqrtf(var + 1e-5f);
  const float sc = lg[o]*inv, sh = lbe[o] - mu*sc;
  #pragma unroll
  for (int b = 0; b < NB; ++b) out[b*256 + o] = fmaxf(z[b]*sc + sh, 0.0f);
}

extern "C" void kernel_launch(void* const* d_in, const int* in_sizes, int n_in,
                              void* d_out, int out_size, void* d_ws, size_t ws_size,
                              hipStream_t stream) {
  const float* pos    = (const float*)d_in[0];
  const float* c1_W1  = (const float*)d_in[2];
  const float* c1_b1  = (const float*)d_in[3];
  const float* c1_g1  = (const float*)d_in[4];
  const float* c1_be1 = (const float*)d_in[5];
  const float* c1_W2  = (const float*)d_in[6];
  const float* c1_b2  = (const float*)d_in[7];
  const float* c2_W1  = (const float*)d_in[8];
  const float* c2_b1  = (const float*)d_in[9];
  const float* c2_g1  = (const float*)d_in[10];
  const float* c2_be1 = (const float*)d_in[11];
  const float* c2_W2  = (const float*)d_in[12];
  const float* c2_b2  = (const float*)d_in[13];
  const float* c2_g2  = (const float*)d_in[14];
  const float* c2_be2 = (const float*)d_in[15];
  const float* c2_W3  = (const float*)d_in[16];
  const float* c2_b3  = (const float*)d_in[17];
  const float* lin_W  = (const float*)d_in[18];
  const float* lin_b  = (const float*)d_in[19];
  const float* lin_g  = (const float*)d_in[20];
  const float* lin_be = (const float*)d_in[21];
  float* out = (float*)d_out;

  char* ws = (char*)d_ws;
  int*   idx     = (int*)  (ws + 0);                 // 512 KB
  float* rel     = (float*)(ws + 524288);            // 1.5 MB
  float* zpart   = (float*)(ws + 2097152 + 2048);    // 8 KB
  float* mid1    = (float*)(ws + 2164736);           // } zeroed by
  float* midA    = (float*)(ws + 2164736 + 4096);    // } wprep
  float* midB    = (float*)(ws + 2164736 + 8192);    // } block 140
  unsigned short* W2T   = (unsigned short*)(ws + 2295808);  // 16 KB (conv2 W2, frag order)
  unsigned short* w1T   = (unsigned short*)(ws + 2312192);  // 8 KB  (conv2 W1, frag order)
  unsigned short* W2c1T = (unsigned short*)(ws + 2320384);  // 8 KB  (conv1 W2, frag order)
  unsigned short* z1h = (unsigned short*)(ws + 2426880);    // 16 MB
  unsigned short* zah = (unsigned short*)(ws + 2426880);    // reuses z1h region (dead)
  float* pmax2   = (float*)(ws + 2426880);                  // 4 MB (after zah dead)
  unsigned short* x1h = (unsigned short*)(ws + 35981312);   // 1 MB fp16
  unsigned short* zhb = (unsigned short*)(ws + 38078464);   // 33.5 MB
  unsigned short* W3T = (unsigned short*)(ws + 71632896);   // 256 KB (frag order)

  wprep_kernel<<<141, 256, 0, stream>>>(c2_W3, c2_W2, c2_W1, c1_W2, W3T, W2T, w1T, W2c1T, mid1);
  knn_conv1_kernel<<<PTS/4, 256, 0, stream>>>(pos, c1_W1, c1_b1, idx, rel, z1h, mid1);
  conv1_l2max_mfma<<<PK/128, 256, 0, stream>>>(z1h, mid1, c1_g1, c1_be1, W2c1T, c1_b2, x1h);
  conv2_l1_mfma<<<PK/128, 256, 0, stream>>>(x1h, idx, rel, w1T, c2_W1, c2_b1, zah, midA);
  conv2_l2_mfma<<<PK/128, 256, 0, stream>>>(zah, midA, c2_g1, c2_be1, W2T, c2_b2, zhb, midB);
  conv2_l3max_mfma<<<PK/128, 256, 0, stream>>>(zhb, midB, c2_g2, c2_be2, W3T, pmax2);
  poollin_kernel<<<NB*4, 256, 0, stream>>>(pmax2, c2_b3, lin_W, zpart);
  final_kernel<<<1, 256, 0, stream>>>(zpart, lin_b, lin_g, lin_be, out);
}